// Round 6
// baseline (836.721 us; speedup 1.0000x reference)
//
#include <hip/hip_runtime.h>

#define NN 100000
#define NE 1000000
#define F_INF 128
#define HID 64
#define NLAY 6
#define NCLS 10
#define NGRAPH 64
#define PART_SZ 12500   // NN/8 — contiguous node range per XCD partition

// ================= CSR build =================
__global__ void k_hist(const int* __restrict__ dst, int* __restrict__ counts, int e) {
    int i = blockIdx.x * 256 + threadIdx.x;
    if (i < e) atomicAdd(&counts[dst[i]], 1);
}

__global__ void k_blocksum(const int* __restrict__ counts, int* __restrict__ bsum, int n) {
    int i = blockIdx.x * 256 + threadIdx.x;
    int v = (i < n) ? counts[i] : 0;
    #pragma unroll
    for (int off = 32; off >= 1; off >>= 1) v += __shfl_down(v, off);
    __shared__ int ws[4];
    if ((threadIdx.x & 63) == 0) ws[threadIdx.x >> 6] = v;
    __syncthreads();
    if (threadIdx.x == 0) bsum[blockIdx.x] = ws[0] + ws[1] + ws[2] + ws[3];
}

__global__ void k_scanbsum(int* __restrict__ bsum, int nb) {   // 1 block, 512 thr
    __shared__ int sh[512];
    int t = threadIdx.x;
    int v = (t < nb) ? bsum[t] : 0;
    sh[t] = v; __syncthreads();
    for (int off = 1; off < 512; off <<= 1) {
        int x = (t >= off) ? sh[t - off] : 0;
        __syncthreads();
        sh[t] += x; __syncthreads();
    }
    if (t < nb) bsum[t] = sh[t] - v;   // exclusive
}

__global__ void k_scanwrite(const int* __restrict__ counts, const int* __restrict__ bsumx,
                            int* __restrict__ rowptr, int* __restrict__ wptr,
                            float* __restrict__ disq, int n, int e) {
    __shared__ int sh[256];
    int t = threadIdx.x;
    int i = blockIdx.x * 256 + t;
    int v = (i < n) ? counts[i] : 0;
    sh[t] = v; __syncthreads();
    for (int off = 1; off < 256; off <<= 1) {
        int x = (t >= off) ? sh[t - off] : 0;
        __syncthreads();
        sh[t] += x; __syncthreads();
    }
    int excl = sh[t] - v + bsumx[blockIdx.x];
    if (i < n) {
        rowptr[i] = excl;
        wptr[i]   = excl;
        disq[i]   = rsqrtf((float)(v + 1));   // +1 self-loop
    }
    if (i == 0) rowptr[n] = e;
}

// XCD-partitioned scatter: block b covers edge chunk b>>3, but only edges whose
// dst falls in node-range partition (b&7). With bid%8 ~ XCD round-robin, all
// stores to a given csr cache line issue from one XCD -> L2 write-combining.
__global__ void k_scatter_part(const int* __restrict__ src, const int* __restrict__ dst,
                               int* __restrict__ wptr, int* __restrict__ csr, int e) {
    int part = blockIdx.x & 7;
    int i = (blockIdx.x >> 3) * 256 + threadIdx.x;
    if (i < e) {
        int d = dst[i];
        if (d / PART_SZ == part) {
            int pos = atomicAdd(&wptr[d], 1);
            csr[pos] = src[i];
        }
    }
}

// ============ dual GEMM (layer 0 only): C = (A@W)*disq[row] ============
__global__ __launch_bounds__(256) void k_gemm_dual(
    const float* __restrict__ A, int lda, int K,
    const float* __restrict__ W,
    const float* __restrict__ disq,
    float* __restrict__ C,
    int n)
{
    __shared__ float Ws[64 * 64];
    __shared__ float As[64 * 68];
    const int tid  = threadIdx.x;
    const int col4 = (tid & 15) * 4;
    const int rowq = tid >> 4;
    const int base = blockIdx.x * 64;

    {
        #pragma unroll
        for (int i = 0; i < 4; i++) {
            float4 v = *(const float4*)(W + (size_t)(i * 256 + tid) * 4);
            *(float4*)(Ws + (size_t)(i * 256 + tid) * 4) = v;
        }
        #pragma unroll
        for (int rr = 0; rr < 4; rr++) {
            int row = base + rowq + rr * 16;
            float4 v = make_float4(0.f, 0.f, 0.f, 0.f);
            if (row < n) v = *(const float4*)(A + (size_t)row * lda + col4);
            *(float4*)(As + (size_t)(rowq + rr * 16) * 68 + col4) = v;
        }
    }
    __syncthreads();

    float4 acc[4];
    #pragma unroll
    for (int r = 0; r < 4; r++) acc[r] = make_float4(0.f, 0.f, 0.f, 0.f);

    for (int k0 = 0; k0 < K; k0 += 64) {
        const bool more = (k0 + 64) < K;
        float4 wreg[4], areg[4];
        if (more) {
            #pragma unroll
            for (int i = 0; i < 4; i++)
                wreg[i] = *(const float4*)(W + (size_t)(k0 + 64) * 64 + (i * 256 + tid) * 4);
            #pragma unroll
            for (int rr = 0; rr < 4; rr++) {
                int row = base + rowq + rr * 16;
                areg[rr] = make_float4(0.f, 0.f, 0.f, 0.f);
                if (row < n) areg[rr] = *(const float4*)(A + (size_t)row * lda + k0 + 64 + col4);
            }
        }
        #pragma unroll 8
        for (int k = 0; k < 64; k++) {
            float4 w = *(const float4*)(Ws + k * 64 + col4);
            float a0 = As[(rowq * 4 + 0) * 68 + k];
            float a1 = As[(rowq * 4 + 1) * 68 + k];
            float a2 = As[(rowq * 4 + 2) * 68 + k];
            float a3 = As[(rowq * 4 + 3) * 68 + k];
            acc[0].x = fmaf(a0, w.x, acc[0].x); acc[0].y = fmaf(a0, w.y, acc[0].y);
            acc[0].z = fmaf(a0, w.z, acc[0].z); acc[0].w = fmaf(a0, w.w, acc[0].w);
            acc[1].x = fmaf(a1, w.x, acc[1].x); acc[1].y = fmaf(a1, w.y, acc[1].y);
            acc[1].z = fmaf(a1, w.z, acc[1].z); acc[1].w = fmaf(a1, w.w, acc[1].w);
            acc[2].x = fmaf(a2, w.x, acc[2].x); acc[2].y = fmaf(a2, w.y, acc[2].y);
            acc[2].z = fmaf(a2, w.z, acc[2].z); acc[2].w = fmaf(a2, w.w, acc[2].w);
            acc[3].x = fmaf(a3, w.x, acc[3].x); acc[3].y = fmaf(a3, w.y, acc[3].y);
            acc[3].z = fmaf(a3, w.z, acc[3].z); acc[3].w = fmaf(a3, w.w, acc[3].w);
        }
        __syncthreads();
        if (more) {
            #pragma unroll
            for (int i = 0; i < 4; i++)
                *(float4*)(Ws + (size_t)(i * 256 + tid) * 4) = wreg[i];
            #pragma unroll
            for (int rr = 0; rr < 4; rr++)
                *(float4*)(As + (size_t)(rowq + rr * 16) * 68 + col4) = areg[rr];
            __syncthreads();
        }
    }

    #pragma unroll
    for (int r = 0; r < 4; r++) {
        int row = base + rowq * 4 + r;
        if (row < n) {
            float s = disq[row];
            float4 o;
            o.x = acc[r].x * s; o.y = acc[r].y * s;
            o.z = acc[r].z * s; o.w = acc[r].w * s;
            *(float4*)(C + (size_t)row * 64 + col4) = o;
        }
    }
}

// ============ fused gather(l-1) + dual-gemm(l): hWin -> [LDS h tile] -> hWout, jkacc ============
__global__ __launch_bounds__(256) void k_fused_gg(
    const int* __restrict__ rowptr, const int* __restrict__ csr,
    const float* __restrict__ hWin,     // hWb_{l-1} [n][64], rows pre-scaled by disq
    const float* __restrict__ disq,
    const float* __restrict__ gbias,    // bias of gather finalize (b_{l-1})
    const float* __restrict__ W,        // Wh block [64][64]
    const float* __restrict__ jkw,      // jkW block [64][64]
    float* __restrict__ hWout,          // [n][64]
    float* __restrict__ jkacc,          // [n][64]
    int jk_mode, int n)                 // 1 = write jkacc, 2 = accumulate
{
    __shared__ float Ws[64 * 64];
    __shared__ float Ws2[64 * 64];
    __shared__ float Hs[64 * 68];
    const int tid  = threadIdx.x;
    const int base = blockIdx.x * 64;

    // stage W + jkw while gather runs
    #pragma unroll
    for (int i = 0; i < 4; i++) {
        *(float4*)(Ws  + (size_t)(i * 256 + tid) * 4) = *(const float4*)(W   + (size_t)(i * 256 + tid) * 4);
        *(float4*)(Ws2 + (size_t)(i * 256 + tid) * 4) = *(const float4*)(jkw + (size_t)(i * 256 + tid) * 4);
    }

    // ---- gather phase: 4 waves x 16 nodes, 16 lanes x float4, 4 edge slots ----
    const float4* hW4 = (const float4*)hWin;
    const int lane = tid & 63;
    const int w    = tid >> 6;
    const int fb   = lane & 15;
    const int es   = lane >> 4;
    float4 gb = ((const float4*)gbias)[fb];

    for (int i = 0; i < 16; i++) {
        int nl   = w * 16 + i;
        int node = base + nl;
        int j = 0, r1 = 0;
        float4 v  = make_float4(0.f, 0.f, 0.f, 0.f);
        float4 v2 = make_float4(0.f, 0.f, 0.f, 0.f);
        if (node < n) {
            j  = rowptr[node];
            r1 = rowptr[node + 1];
            if (es == 0) v = hW4[(size_t)node * 16 + fb];    // self-loop
        }
        while (j < r1) {
            int cnt = min(r1 - j, 64);
            int idx = (lane < cnt) ? csr[j + lane] : 0;
            int jj = 0;
            for (; jj + 8 <= cnt; jj += 8) {
                int s0 = __shfl(idx, jj + es);
                int s1 = __shfl(idx, jj + 4 + es);
                float4 t0 = hW4[(size_t)s0 * 16 + fb];
                float4 t1 = hW4[(size_t)s1 * 16 + fb];
                v.x  += t0.x; v.y  += t0.y; v.z  += t0.z; v.w  += t0.w;
                v2.x += t1.x; v2.y += t1.y; v2.z += t1.z; v2.w += t1.w;
            }
            for (; jj < cnt; jj += 4) {
                int sidx = jj + es;
                int s = __shfl(idx, (sidx < cnt) ? sidx : 0);
                if (sidx < cnt) {
                    float4 t = hW4[(size_t)s * 16 + fb];
                    v.x += t.x; v.y += t.y; v.z += t.z; v.w += t.w;
                }
            }
            j += cnt;
        }
        v.x += v2.x; v.y += v2.y; v.z += v2.z; v.w += v2.w;
        v.x += __shfl_xor(v.x, 16); v.y += __shfl_xor(v.y, 16);
        v.z += __shfl_xor(v.z, 16); v.w += __shfl_xor(v.w, 16);
        v.x += __shfl_xor(v.x, 32); v.y += __shfl_xor(v.y, 32);
        v.z += __shfl_xor(v.z, 32); v.w += __shfl_xor(v.w, 32);
        if (es == 0) {
            float4 o = make_float4(0.f, 0.f, 0.f, 0.f);
            if (node < n) {
                float s = disq[node];
                o.x = fmaxf(fmaf(s, v.x, gb.x), 0.f);
                o.y = fmaxf(fmaf(s, v.y, gb.y), 0.f);
                o.z = fmaxf(fmaf(s, v.z, gb.z), 0.f);
                o.w = fmaxf(fmaf(s, v.w, gb.w), 0.f);
            }
            *(float4*)(Hs + (size_t)nl * 68 + fb * 4) = o;
        }
    }
    __syncthreads();

    // ---- gemm phase: K=64 dual (W and jkw), A tile already in LDS ----
    const int col4 = (tid & 15) * 4;
    const int rowq = tid >> 4;
    float4 acc[4], acc2[4];
    #pragma unroll
    for (int r = 0; r < 4; r++) {
        acc[r]  = make_float4(0.f, 0.f, 0.f, 0.f);
        acc2[r] = make_float4(0.f, 0.f, 0.f, 0.f);
    }
    #pragma unroll 4
    for (int k = 0; k < 64; k++) {
        float4 wv = *(const float4*)(Ws  + k * 64 + col4);
        float4 w2 = *(const float4*)(Ws2 + k * 64 + col4);
        float a0 = Hs[(rowq * 4 + 0) * 68 + k];
        float a1 = Hs[(rowq * 4 + 1) * 68 + k];
        float a2 = Hs[(rowq * 4 + 2) * 68 + k];
        float a3 = Hs[(rowq * 4 + 3) * 68 + k];
        acc[0].x = fmaf(a0, wv.x, acc[0].x); acc[0].y = fmaf(a0, wv.y, acc[0].y);
        acc[0].z = fmaf(a0, wv.z, acc[0].z); acc[0].w = fmaf(a0, wv.w, acc[0].w);
        acc[1].x = fmaf(a1, wv.x, acc[1].x); acc[1].y = fmaf(a1, wv.y, acc[1].y);
        acc[1].z = fmaf(a1, wv.z, acc[1].z); acc[1].w = fmaf(a1, wv.w, acc[1].w);
        acc[2].x = fmaf(a2, wv.x, acc[2].x); acc[2].y = fmaf(a2, wv.y, acc[2].y);
        acc[2].z = fmaf(a2, wv.z, acc[2].z); acc[2].w = fmaf(a2, wv.w, acc[2].w);
        acc[3].x = fmaf(a3, wv.x, acc[3].x); acc[3].y = fmaf(a3, wv.y, acc[3].y);
        acc[3].z = fmaf(a3, wv.z, acc[3].z); acc[3].w = fmaf(a3, wv.w, acc[3].w);
        acc2[0].x = fmaf(a0, w2.x, acc2[0].x); acc2[0].y = fmaf(a0, w2.y, acc2[0].y);
        acc2[0].z = fmaf(a0, w2.z, acc2[0].z); acc2[0].w = fmaf(a0, w2.w, acc2[0].w);
        acc2[1].x = fmaf(a1, w2.x, acc2[1].x); acc2[1].y = fmaf(a1, w2.y, acc2[1].y);
        acc2[1].z = fmaf(a1, w2.z, acc2[1].z); acc2[1].w = fmaf(a1, w2.w, acc2[1].w);
        acc2[2].x = fmaf(a2, w2.x, acc2[2].x); acc2[2].y = fmaf(a2, w2.y, acc2[2].y);
        acc2[2].z = fmaf(a2, w2.z, acc2[2].z); acc2[2].w = fmaf(a2, w2.w, acc2[2].w);
        acc2[3].x = fmaf(a3, w2.x, acc2[3].x); acc2[3].y = fmaf(a3, w2.y, acc2[3].y);
        acc2[3].z = fmaf(a3, w2.z, acc2[3].z); acc2[3].w = fmaf(a3, w2.w, acc2[3].w);
    }

    #pragma unroll
    for (int r = 0; r < 4; r++) {
        int row = base + rowq * 4 + r;
        if (row < n) {
            float s = disq[row];
            float4 o;
            o.x = acc[r].x * s; o.y = acc[r].y * s;
            o.z = acc[r].z * s; o.w = acc[r].w * s;
            *(float4*)(hWout + (size_t)row * 64 + col4) = o;
            if (jk_mode == 1) {
                *(float4*)(jkacc + (size_t)row * 64 + col4) = acc2[r];
            } else {
                float4 p = *(const float4*)(jkacc + (size_t)row * 64 + col4);
                p.x += acc2[r].x; p.y += acc2[r].y;
                p.z += acc2[r].z; p.w += acc2[r].w;
                *(float4*)(jkacc + (size_t)row * 64 + col4) = p;
            }
        }
    }
}

// ============ final gather (layer 5): writes h5 to global ============
__global__ __launch_bounds__(256) void k_gather(
    const int* __restrict__ rowptr, const int* __restrict__ csr,
    const float* __restrict__ hW, const float* __restrict__ disq,
    const float* __restrict__ bias, float* __restrict__ hout, int n)
{
    const float4* hW4 = (const float4*)hW;
    int wid  = (blockIdx.x * 256 + threadIdx.x) >> 6;
    if (wid >= n) return;
    int lane = threadIdx.x & 63;
    int fb = lane & 15;
    int es = lane >> 4;
    int j  = rowptr[wid];
    int r1 = rowptr[wid + 1];
    float4 v  = make_float4(0.f, 0.f, 0.f, 0.f);
    float4 v2 = make_float4(0.f, 0.f, 0.f, 0.f);
    if (es == 0) v = hW4[(size_t)wid * 16 + fb];
    while (j < r1) {
        int cnt = min(r1 - j, 64);
        int idx = (lane < cnt) ? csr[j + lane] : 0;
        int jj = 0;
        for (; jj + 8 <= cnt; jj += 8) {
            int s0 = __shfl(idx, jj + es);
            int s1 = __shfl(idx, jj + 4 + es);
            float4 t0 = hW4[(size_t)s0 * 16 + fb];
            float4 t1 = hW4[(size_t)s1 * 16 + fb];
            v.x  += t0.x; v.y  += t0.y; v.z  += t0.z; v.w  += t0.w;
            v2.x += t1.x; v2.y += t1.y; v2.z += t1.z; v2.w += t1.w;
        }
        for (; jj < cnt; jj += 4) {
            int sidx = jj + es;
            int s = __shfl(idx, (sidx < cnt) ? sidx : 0);
            if (sidx < cnt) {
                float4 t = hW4[(size_t)s * 16 + fb];
                v.x += t.x; v.y += t.y; v.z += t.z; v.w += t.w;
            }
        }
        j += cnt;
    }
    v.x += v2.x; v.y += v2.y; v.z += v2.z; v.w += v2.w;
    v.x += __shfl_xor(v.x, 16); v.y += __shfl_xor(v.y, 16);
    v.z += __shfl_xor(v.z, 16); v.w += __shfl_xor(v.w, 16);
    v.x += __shfl_xor(v.x, 32); v.y += __shfl_xor(v.y, 32);
    v.z += __shfl_xor(v.z, 32); v.w += __shfl_xor(v.w, 32);
    if (es == 0) {
        float s = disq[wid];
        float4 b = ((const float4*)bias)[fb];
        float4 o;
        o.x = fmaxf(fmaf(s, v.x, b.x), 0.f);
        o.y = fmaxf(fmaf(s, v.y, b.y), 0.f);
        o.z = fmaxf(fmaf(s, v.z, b.z), 0.f);
        o.w = fmaxf(fmaf(s, v.w, b.w), 0.f);
        ((float4*)hout)[(size_t)wid * 16 + fb] = o;
    }
}

// ============ final: t = relu(h@jkW5 + jkacc + jkb); pool by batch (LDS pre-reduce) ============
__global__ __launch_bounds__(256) void k_jkfin_pool(
    const float* __restrict__ A,
    const float* __restrict__ W,
    const float* __restrict__ jkacc,
    const float* __restrict__ bias,
    const int* __restrict__ batch,
    float* __restrict__ pooled,
    int n)
{
    __shared__ float Ws[64 * 64];
    __shared__ float As[64 * 68];
    const int tid  = threadIdx.x;
    const int col4 = (tid & 15) * 4;
    const int rowq = tid >> 4;
    const int base = blockIdx.x * 64;

    #pragma unroll
    for (int i = 0; i < 4; i++) {
        float4 v = *(const float4*)(W + (size_t)(i * 256 + tid) * 4);
        *(float4*)(Ws + (size_t)(i * 256 + tid) * 4) = v;
    }
    #pragma unroll
    for (int rr = 0; rr < 4; rr++) {
        int row = base + rowq + rr * 16;
        float4 v = make_float4(0.f, 0.f, 0.f, 0.f);
        if (row < n) v = *(const float4*)(A + (size_t)row * 64 + col4);
        *(float4*)(As + (size_t)(rowq + rr * 16) * 68 + col4) = v;
    }
    __syncthreads();

    float4 acc[4];
    #pragma unroll
    for (int r = 0; r < 4; r++) acc[r] = make_float4(0.f, 0.f, 0.f, 0.f);
    #pragma unroll 8
    for (int k = 0; k < 64; k++) {
        float4 w = *(const float4*)(Ws + k * 64 + col4);
        float a0 = As[(rowq * 4 + 0) * 68 + k];
        float a1 = As[(rowq * 4 + 1) * 68 + k];
        float a2 = As[(rowq * 4 + 2) * 68 + k];
        float a3 = As[(rowq * 4 + 3) * 68 + k];
        acc[0].x = fmaf(a0, w.x, acc[0].x); acc[0].y = fmaf(a0, w.y, acc[0].y);
        acc[0].z = fmaf(a0, w.z, acc[0].z); acc[0].w = fmaf(a0, w.w, acc[0].w);
        acc[1].x = fmaf(a1, w.x, acc[1].x); acc[1].y = fmaf(a1, w.y, acc[1].y);
        acc[1].z = fmaf(a1, w.z, acc[1].z); acc[1].w = fmaf(a1, w.w, acc[1].w);
        acc[2].x = fmaf(a2, w.x, acc[2].x); acc[2].y = fmaf(a2, w.y, acc[2].y);
        acc[2].z = fmaf(a2, w.z, acc[2].z); acc[2].w = fmaf(a2, w.w, acc[2].w);
        acc[3].x = fmaf(a3, w.x, acc[3].x); acc[3].y = fmaf(a3, w.y, acc[3].y);
        acc[3].z = fmaf(a3, w.z, acc[3].z); acc[3].w = fmaf(a3, w.w, acc[3].w);
    }
    __syncthreads();               // Ws/As dead; reuse Ws as the pooling slab

    float* slab = Ws;              // [64 graphs][64 cols]
    #pragma unroll
    for (int i = tid; i < 4096; i += 256) slab[i] = 0.f;
    __syncthreads();

    float4 bb = *(const float4*)(bias + col4);
    int curg = -1;
    float4 s4 = make_float4(0.f, 0.f, 0.f, 0.f);
    #pragma unroll
    for (int r = 0; r < 4; r++) {
        int row = base + rowq * 4 + r;
        if (row < n) {
            float4 p = *(const float4*)(jkacc + (size_t)row * 64 + col4);
            float4 vv;
            vv.x = fmaxf(acc[r].x + p.x + bb.x, 0.f);
            vv.y = fmaxf(acc[r].y + p.y + bb.y, 0.f);
            vv.z = fmaxf(acc[r].z + p.z + bb.z, 0.f);
            vv.w = fmaxf(acc[r].w + p.w + bb.w, 0.f);
            int g = batch[row];
            if (g != curg) {
                if (curg >= 0) {
                    atomicAdd(&slab[curg * 64 + col4 + 0], s4.x);
                    atomicAdd(&slab[curg * 64 + col4 + 1], s4.y);
                    atomicAdd(&slab[curg * 64 + col4 + 2], s4.z);
                    atomicAdd(&slab[curg * 64 + col4 + 3], s4.w);
                }
                curg = g; s4 = vv;
            } else {
                s4.x += vv.x; s4.y += vv.y; s4.z += vv.z; s4.w += vv.w;
            }
        }
    }
    if (curg >= 0) {
        atomicAdd(&slab[curg * 64 + col4 + 0], s4.x);
        atomicAdd(&slab[curg * 64 + col4 + 1], s4.y);
        atomicAdd(&slab[curg * 64 + col4 + 2], s4.z);
        atomicAdd(&slab[curg * 64 + col4 + 3], s4.w);
    }
    __syncthreads();

    int g0 = batch[base];
    int g1 = batch[(base + 63 < n) ? (base + 63) : (n - 1)];
    int cnt = (g1 - g0 + 1) * 64;
    for (int i = tid; i < cnt; i += 256) {
        int g = g0 + (i >> 6);
        int c = i & 63;
        float v = slab[g * 64 + c];
        if (v != 0.f) atomicAdd(&pooled[g * 64 + c], v);
    }
}

// ============ head ============
__global__ void k_head(
    const float* __restrict__ pooled,
    const float* __restrict__ W1, const float* __restrict__ b1,
    const float* __restrict__ W2, const float* __restrict__ b2,
    float* __restrict__ out)
{
    int g = threadIdx.x;
    float p[64];
    #pragma unroll
    for (int k = 0; k < 64; k++) p[k] = pooled[g * 64 + k];
    float h1[64];
    #pragma unroll
    for (int j = 0; j < 64; j++) {
        float acc = b1[j];
        #pragma unroll
        for (int k = 0; k < 64; k++) acc = fmaf(p[k], W1[k * 64 + j], acc);
        h1[j] = fmaxf(acc, 0.f);
    }
    float lg[10];
    float mx = -1e30f;
    #pragma unroll
    for (int c = 0; c < 10; c++) {
        float acc = b2[c];
        #pragma unroll
        for (int j = 0; j < 64; j++) acc = fmaf(h1[j], W2[j * 10 + c], acc);
        lg[c] = acc;
        mx = fmaxf(mx, acc);
    }
    float ssum = 0.f;
    #pragma unroll
    for (int c = 0; c < 10; c++) { lg[c] = __expf(lg[c] - mx); ssum += lg[c]; }
    float inv = 1.0f / ssum;
    #pragma unroll
    for (int c = 0; c < 10; c++) out[g * 10 + c] = lg[c] * inv;
}

extern "C" void kernel_launch(void* const* d_in, const int* in_sizes, int n_in,
                              void* d_out, int out_size, void* d_ws, size_t ws_size,
                              hipStream_t stream) {
    (void)in_sizes; (void)n_in; (void)out_size; (void)ws_size;
    const float* x     = (const float*)d_in[0];
    const int*   ei    = (const int*)d_in[1];
    const int*   batch = (const int*)d_in[2];
    const float* W0    = (const float*)d_in[3];
    const float* b0    = (const float*)d_in[4];
    const float* Wh    = (const float*)d_in[5];
    const float* bh    = (const float*)d_in[6];
    const float* jkW   = (const float*)d_in[7];   // [384][64] = 6 stacked [64][64]
    const float* jkb   = (const float*)d_in[8];
    const float* W1    = (const float*)d_in[9];
    const float* b1    = (const float*)d_in[10];
    const float* W2    = (const float*)d_in[11];
    const float* b2    = (const float*)d_in[12];

    const int* src = ei;
    const int* dst = ei + NE;

    float* fws    = (float*)d_ws;
    float* disq   = fws;                                // 100352
    float* hWbA   = disq + 100352;                      // NN*64
    float* hWbB   = hWbA + (size_t)NN * 64;             // NN*64
    float* h5     = hWbB + (size_t)NN * 64;             // NN*64
    float* jkacc  = h5 + (size_t)NN * 64;               // NN*64
    float* pooled = jkacc + (size_t)NN * 64;            // 4096
    int*   counts = (int*)(pooled + 4096);              // 100352
    int*   rowptr = counts + 100352;                    // NN+1
    int*   wptr   = rowptr + 100352;                    // 100352
    int*   bsum   = wptr + 100352;                      // 512
    int*   csr    = bsum + 512;                         // NE

    const int NB_N = (NN + 255) / 256;                  // 391
    const int NB_E = (NE + 255) / 256;                  // 3907

    // ---- CSR build ----
    hipMemsetAsync(counts, 0, (size_t)NN * sizeof(int), stream);
    k_hist<<<NB_E, 256, 0, stream>>>(dst, counts, NE);
    k_blocksum<<<NB_N, 256, 0, stream>>>(counts, bsum, NN);
    k_scanbsum<<<1, 512, 0, stream>>>(bsum, NB_N);
    k_scanwrite<<<NB_N, 256, 0, stream>>>(counts, bsum, rowptr, wptr, disq, NN, NE);
    k_scatter_part<<<NB_E * 8, 256, 0, stream>>>(src, dst, wptr, csr, NE);

    const int gemm_grid   = (NN + 63) / 64;             // 1563
    const int gather_grid = (NN + 3) / 4;               // 25000

    // layer 0 gemm: hWbA = (x @ W0) * disq
    k_gemm_dual<<<gemm_grid, 256, 0, stream>>>(x, F_INF, F_INF, W0, disq, hWbA, NN);

    // fused layers 1..5: gather(l-1) + gemm(l), ping-pong hWbA/hWbB
    float* bufs[2] = { hWbA, hWbB };
    for (int l = 1; l < NLAY; l++) {
        const float* gb  = (l == 1) ? b0 : (bh + (size_t)(l - 2) * 64);
        const float* W   = Wh + (size_t)(l - 1) * 64 * 64;
        const float* jw  = jkW + (size_t)(l - 1) * 64 * 64;
        int          jkm = (l == 1) ? 1 : 2;
        k_fused_gg<<<gemm_grid, 256, 0, stream>>>(rowptr, csr, bufs[(l - 1) & 1],
                                                  disq, gb, W, jw,
                                                  bufs[l & 1], jkacc, jkm, NN);
    }

    // final gather: h5 = relu(disq*agg(hWb5) + bh[4])
    k_gather<<<gather_grid, 256, 0, stream>>>(rowptr, csr, bufs[5 & 1], disq,
                                              bh + (size_t)4 * 64, h5, NN);

    hipMemsetAsync(pooled, 0, 64 * 64 * sizeof(float), stream);
    k_jkfin_pool<<<gemm_grid, 256, 0, stream>>>(h5, jkW + (size_t)5 * 64 * 64, jkacc,
                                                jkb, batch, pooled, NN);
    k_head<<<1, 64, 0, stream>>>(pooled, W1, b1, W2, b2, (float*)d_out);
}

// Round 7
// 582.536 us; speedup vs baseline: 1.4363x; 1.4363x over previous
//
#include <hip/hip_runtime.h>
#include <hip/hip_fp16.h>

#define NN 100000
#define NE 1000000
#define F_INF 128
#define HID 64
#define NLAY 6
#define NCLS 10
#define NGRAPH 64
#define PART_SZ 12500   // NN/8 — contiguous node range per XCD partition

__device__ __forceinline__ float4 h4f(ushort4 u) {
    __half2 lo = *reinterpret_cast<__half2*>(&u);
    __half2 hi = *reinterpret_cast<__half2*>(reinterpret_cast<unsigned short*>(&u) + 2);
    float2 a = __half22float2(lo);
    float2 b = __half22float2(hi);
    return make_float4(a.x, a.y, b.x, b.y);
}

__device__ __forceinline__ ushort4 f4h(float4 v) {
    __half2 lo = __floats2half2_rn(v.x, v.y);
    __half2 hi = __floats2half2_rn(v.z, v.w);
    ushort4 u;
    *reinterpret_cast<__half2*>(&u) = lo;
    *reinterpret_cast<__half2*>(reinterpret_cast<unsigned short*>(&u) + 2) = hi;
    return u;
}

// ================= CSR build =================
__global__ void k_hist(const int* __restrict__ dst, int* __restrict__ counts, int e) {
    int i = blockIdx.x * 256 + threadIdx.x;
    if (i < e) atomicAdd(&counts[dst[i]], 1);
}

__global__ void k_blocksum(const int* __restrict__ counts, int* __restrict__ bsum, int n) {
    int i = blockIdx.x * 256 + threadIdx.x;
    int v = (i < n) ? counts[i] : 0;
    #pragma unroll
    for (int off = 32; off >= 1; off >>= 1) v += __shfl_down(v, off);
    __shared__ int ws[4];
    if ((threadIdx.x & 63) == 0) ws[threadIdx.x >> 6] = v;
    __syncthreads();
    if (threadIdx.x == 0) bsum[blockIdx.x] = ws[0] + ws[1] + ws[2] + ws[3];
}

__global__ void k_scanbsum(int* __restrict__ bsum, int nb) {   // 1 block, 512 thr
    __shared__ int sh[512];
    int t = threadIdx.x;
    int v = (t < nb) ? bsum[t] : 0;
    sh[t] = v; __syncthreads();
    for (int off = 1; off < 512; off <<= 1) {
        int x = (t >= off) ? sh[t - off] : 0;
        __syncthreads();
        sh[t] += x; __syncthreads();
    }
    if (t < nb) bsum[t] = sh[t] - v;   // exclusive
}

__global__ void k_scanwrite(const int* __restrict__ counts, const int* __restrict__ bsumx,
                            int* __restrict__ rowptr, int* __restrict__ wptr,
                            float* __restrict__ disq, int n, int e) {
    __shared__ int sh[256];
    int t = threadIdx.x;
    int i = blockIdx.x * 256 + t;
    int v = (i < n) ? counts[i] : 0;
    sh[t] = v; __syncthreads();
    for (int off = 1; off < 256; off <<= 1) {
        int x = (t >= off) ? sh[t - off] : 0;
        __syncthreads();
        sh[t] += x; __syncthreads();
    }
    int excl = sh[t] - v + bsumx[blockIdx.x];
    if (i < n) {
        rowptr[i] = excl;
        wptr[i]   = excl;
        disq[i]   = rsqrtf((float)(v + 1));   // +1 self-loop
    }
    if (i == 0) rowptr[n] = e;
}

// XCD-partitioned scatter (R6-verified): stores to a csr line issue from one XCD
__global__ void k_scatter_part(const int* __restrict__ src, const int* __restrict__ dst,
                               int* __restrict__ wptr, int* __restrict__ csr, int e) {
    int part = blockIdx.x & 7;
    int i = (blockIdx.x >> 3) * 256 + threadIdx.x;
    if (i < e) {
        int d = dst[i];
        if (d / PART_SZ == part) {
            int pos = atomicAdd(&wptr[d], 1);
            csr[pos] = src[i];
        }
    }
}

// ============ dual GEMM: C16 = fp16((A@W)*disq[row]); optionally jkacc (+)= A@jkw ============
// jk_mode: 0 none, 1 write jkacc, 2 accumulate. A is fp32.
__global__ __launch_bounds__(256) void k_gemm_dual(
    const float* __restrict__ A, int lda, int K,
    const float* __restrict__ W,
    const float* __restrict__ jkw,
    const float* __restrict__ disq,
    unsigned short* __restrict__ C16,    // [n][64] fp16
    float* __restrict__ jkacc,           // [n][64] fp32
    int jk_mode, int n)
{
    __shared__ float Ws[64 * 64];
    __shared__ float Ws2[64 * 64];
    __shared__ float As[64 * 68];
    const int tid  = threadIdx.x;
    const int col4 = (tid & 15) * 4;
    const int rowq = tid >> 4;
    const int base = blockIdx.x * 64;

    {
        #pragma unroll
        for (int i = 0; i < 4; i++) {
            float4 v = *(const float4*)(W + (size_t)(i * 256 + tid) * 4);
            *(float4*)(Ws + (size_t)(i * 256 + tid) * 4) = v;
        }
        if (jk_mode) {
            #pragma unroll
            for (int i = 0; i < 4; i++) {
                float4 v = *(const float4*)(jkw + (size_t)(i * 256 + tid) * 4);
                *(float4*)(Ws2 + (size_t)(i * 256 + tid) * 4) = v;
            }
        }
        #pragma unroll
        for (int rr = 0; rr < 4; rr++) {
            int row = base + rowq + rr * 16;
            float4 v = make_float4(0.f, 0.f, 0.f, 0.f);
            if (row < n) v = *(const float4*)(A + (size_t)row * lda + col4);
            *(float4*)(As + (size_t)(rowq + rr * 16) * 68 + col4) = v;
        }
    }
    __syncthreads();

    float4 acc[4], acc2[4];
    #pragma unroll
    for (int r = 0; r < 4; r++) {
        acc[r]  = make_float4(0.f, 0.f, 0.f, 0.f);
        acc2[r] = make_float4(0.f, 0.f, 0.f, 0.f);
    }

    for (int k0 = 0; k0 < K; k0 += 64) {
        const bool more = (k0 + 64) < K;
        float4 wreg[4], areg[4];
        if (more) {
            #pragma unroll
            for (int i = 0; i < 4; i++)
                wreg[i] = *(const float4*)(W + (size_t)(k0 + 64) * 64 + (i * 256 + tid) * 4);
            #pragma unroll
            for (int rr = 0; rr < 4; rr++) {
                int row = base + rowq + rr * 16;
                areg[rr] = make_float4(0.f, 0.f, 0.f, 0.f);
                if (row < n) areg[rr] = *(const float4*)(A + (size_t)row * lda + k0 + 64 + col4);
            }
        }
        if (jk_mode && k0 == 0) {
            #pragma unroll 4
            for (int k = 0; k < 64; k++) {
                float4 w  = *(const float4*)(Ws  + k * 64 + col4);
                float4 w2 = *(const float4*)(Ws2 + k * 64 + col4);
                float a0 = As[(rowq * 4 + 0) * 68 + k];
                float a1 = As[(rowq * 4 + 1) * 68 + k];
                float a2 = As[(rowq * 4 + 2) * 68 + k];
                float a3 = As[(rowq * 4 + 3) * 68 + k];
                acc[0].x = fmaf(a0, w.x, acc[0].x); acc[0].y = fmaf(a0, w.y, acc[0].y);
                acc[0].z = fmaf(a0, w.z, acc[0].z); acc[0].w = fmaf(a0, w.w, acc[0].w);
                acc[1].x = fmaf(a1, w.x, acc[1].x); acc[1].y = fmaf(a1, w.y, acc[1].y);
                acc[1].z = fmaf(a1, w.z, acc[1].z); acc[1].w = fmaf(a1, w.w, acc[1].w);
                acc[2].x = fmaf(a2, w.x, acc[2].x); acc[2].y = fmaf(a2, w.y, acc[2].y);
                acc[2].z = fmaf(a2, w.z, acc[2].z); acc[2].w = fmaf(a2, w.w, acc[2].w);
                acc[3].x = fmaf(a3, w.x, acc[3].x); acc[3].y = fmaf(a3, w.y, acc[3].y);
                acc[3].z = fmaf(a3, w.z, acc[3].z); acc[3].w = fmaf(a3, w.w, acc[3].w);
                acc2[0].x = fmaf(a0, w2.x, acc2[0].x); acc2[0].y = fmaf(a0, w2.y, acc2[0].y);
                acc2[0].z = fmaf(a0, w2.z, acc2[0].z); acc2[0].w = fmaf(a0, w2.w, acc2[0].w);
                acc2[1].x = fmaf(a1, w2.x, acc2[1].x); acc2[1].y = fmaf(a1, w2.y, acc2[1].y);
                acc2[1].z = fmaf(a1, w2.z, acc2[1].z); acc2[1].w = fmaf(a1, w2.w, acc2[1].w);
                acc2[2].x = fmaf(a2, w2.x, acc2[2].x); acc2[2].y = fmaf(a2, w2.y, acc2[2].y);
                acc2[2].z = fmaf(a2, w2.z, acc2[2].z); acc2[2].w = fmaf(a2, w2.w, acc2[2].w);
                acc2[3].x = fmaf(a3, w2.x, acc2[3].x); acc2[3].y = fmaf(a3, w2.y, acc2[3].y);
                acc2[3].z = fmaf(a3, w2.z, acc2[3].z); acc2[3].w = fmaf(a3, w2.w, acc2[3].w);
            }
        } else {
            #pragma unroll 8
            for (int k = 0; k < 64; k++) {
                float4 w = *(const float4*)(Ws + k * 64 + col4);
                float a0 = As[(rowq * 4 + 0) * 68 + k];
                float a1 = As[(rowq * 4 + 1) * 68 + k];
                float a2 = As[(rowq * 4 + 2) * 68 + k];
                float a3 = As[(rowq * 4 + 3) * 68 + k];
                acc[0].x = fmaf(a0, w.x, acc[0].x); acc[0].y = fmaf(a0, w.y, acc[0].y);
                acc[0].z = fmaf(a0, w.z, acc[0].z); acc[0].w = fmaf(a0, w.w, acc[0].w);
                acc[1].x = fmaf(a1, w.x, acc[1].x); acc[1].y = fmaf(a1, w.y, acc[1].y);
                acc[1].z = fmaf(a1, w.z, acc[1].z); acc[1].w = fmaf(a1, w.w, acc[1].w);
                acc[2].x = fmaf(a2, w.x, acc[2].x); acc[2].y = fmaf(a2, w.y, acc[2].y);
                acc[2].z = fmaf(a2, w.z, acc[2].z); acc[2].w = fmaf(a2, w.w, acc[2].w);
                acc[3].x = fmaf(a3, w.x, acc[3].x); acc[3].y = fmaf(a3, w.y, acc[3].y);
                acc[3].z = fmaf(a3, w.z, acc[3].z); acc[3].w = fmaf(a3, w.w, acc[3].w);
            }
        }
        __syncthreads();
        if (more) {
            #pragma unroll
            for (int i = 0; i < 4; i++)
                *(float4*)(Ws + (size_t)(i * 256 + tid) * 4) = wreg[i];
            #pragma unroll
            for (int rr = 0; rr < 4; rr++)
                *(float4*)(As + (size_t)(rowq + rr * 16) * 68 + col4) = areg[rr];
            __syncthreads();
        }
    }

    #pragma unroll
    for (int r = 0; r < 4; r++) {
        int row = base + rowq * 4 + r;
        if (row < n) {
            float s = disq[row];
            float4 o;
            o.x = acc[r].x * s; o.y = acc[r].y * s;
            o.z = acc[r].z * s; o.w = acc[r].w * s;
            ((ushort4*)C16)[(size_t)row * 16 + (tid & 15)] = f4h(o);
            if (jk_mode == 1) {
                *(float4*)(jkacc + (size_t)row * 64 + col4) = acc2[r];
            } else if (jk_mode == 2) {
                float4 p = *(const float4*)(jkacc + (size_t)row * 64 + col4);
                p.x += acc2[r].x; p.y += acc2[r].y;
                p.z += acc2[r].z; p.w += acc2[r].w;
                *(float4*)(jkacc + (size_t)row * 64 + col4) = p;
            }
        }
    }
}

// ============ gather: wave per node, fp16 input, 16 lanes x 8B, 4 edge slots ============
__global__ __launch_bounds__(256) void k_gather(
    const int* __restrict__ rowptr, const int* __restrict__ csr,
    const unsigned short* __restrict__ hW16, const float* __restrict__ disq,
    const float* __restrict__ bias, float* __restrict__ hout, int n)
{
    const ushort4* hW4 = (const ushort4*)hW16;
    int wid  = (blockIdx.x * 256 + threadIdx.x) >> 6;
    if (wid >= n) return;
    int lane = threadIdx.x & 63;
    int fb = lane & 15;       // 8B chunk index within 128B row
    int es = lane >> 4;       // edge slot 0..3
    int j  = rowptr[wid];
    int r1 = rowptr[wid + 1];
    float4 v  = make_float4(0.f, 0.f, 0.f, 0.f);
    float4 v2 = make_float4(0.f, 0.f, 0.f, 0.f);
    if (es == 0) v = h4f(hW4[(size_t)wid * 16 + fb]);    // self-loop
    while (j < r1) {
        int cnt = min(r1 - j, 64);
        int idx = (lane < cnt) ? csr[j + lane] : 0;
        int jj = 0;
        for (; jj + 8 <= cnt; jj += 8) {
            int s0 = __shfl(idx, jj + es);
            int s1 = __shfl(idx, jj + 4 + es);
            float4 t0 = h4f(hW4[(size_t)s0 * 16 + fb]);
            float4 t1 = h4f(hW4[(size_t)s1 * 16 + fb]);
            v.x  += t0.x; v.y  += t0.y; v.z  += t0.z; v.w  += t0.w;
            v2.x += t1.x; v2.y += t1.y; v2.z += t1.z; v2.w += t1.w;
        }
        for (; jj < cnt; jj += 4) {
            int sidx = jj + es;
            int s = __shfl(idx, (sidx < cnt) ? sidx : 0);
            if (sidx < cnt) {
                float4 t = h4f(hW4[(size_t)s * 16 + fb]);
                v.x += t.x; v.y += t.y; v.z += t.z; v.w += t.w;
            }
        }
        j += cnt;
    }
    v.x += v2.x; v.y += v2.y; v.z += v2.z; v.w += v2.w;
    v.x += __shfl_xor(v.x, 16); v.y += __shfl_xor(v.y, 16);
    v.z += __shfl_xor(v.z, 16); v.w += __shfl_xor(v.w, 16);
    v.x += __shfl_xor(v.x, 32); v.y += __shfl_xor(v.y, 32);
    v.z += __shfl_xor(v.z, 32); v.w += __shfl_xor(v.w, 32);
    if (es == 0) {
        float s = disq[wid];
        float4 b = ((const float4*)bias)[fb];
        float4 o;
        o.x = fmaxf(fmaf(s, v.x, b.x), 0.f);
        o.y = fmaxf(fmaf(s, v.y, b.y), 0.f);
        o.z = fmaxf(fmaf(s, v.z, b.z), 0.f);
        o.w = fmaxf(fmaf(s, v.w, b.w), 0.f);
        ((float4*)hout)[(size_t)wid * 16 + fb] = o;
    }
}

// ============ final: t = relu(h@jkW5 + jkacc + jkb); pool by batch (LDS pre-reduce) ============
__global__ __launch_bounds__(256) void k_jkfin_pool(
    const float* __restrict__ A,
    const float* __restrict__ W,
    const float* __restrict__ jkacc,
    const float* __restrict__ bias,
    const int* __restrict__ batch,
    float* __restrict__ pooled,
    int n)
{
    __shared__ float Ws[64 * 64];
    __shared__ float As[64 * 68];
    const int tid  = threadIdx.x;
    const int col4 = (tid & 15) * 4;
    const int rowq = tid >> 4;
    const int base = blockIdx.x * 64;

    #pragma unroll
    for (int i = 0; i < 4; i++) {
        float4 v = *(const float4*)(W + (size_t)(i * 256 + tid) * 4);
        *(float4*)(Ws + (size_t)(i * 256 + tid) * 4) = v;
    }
    #pragma unroll
    for (int rr = 0; rr < 4; rr++) {
        int row = base + rowq + rr * 16;
        float4 v = make_float4(0.f, 0.f, 0.f, 0.f);
        if (row < n) v = *(const float4*)(A + (size_t)row * 64 + col4);
        *(float4*)(As + (size_t)(rowq + rr * 16) * 68 + col4) = v;
    }
    __syncthreads();

    float4 acc[4];
    #pragma unroll
    for (int r = 0; r < 4; r++) acc[r] = make_float4(0.f, 0.f, 0.f, 0.f);
    #pragma unroll 8
    for (int k = 0; k < 64; k++) {
        float4 w = *(const float4*)(Ws + k * 64 + col4);
        float a0 = As[(rowq * 4 + 0) * 68 + k];
        float a1 = As[(rowq * 4 + 1) * 68 + k];
        float a2 = As[(rowq * 4 + 2) * 68 + k];
        float a3 = As[(rowq * 4 + 3) * 68 + k];
        acc[0].x = fmaf(a0, w.x, acc[0].x); acc[0].y = fmaf(a0, w.y, acc[0].y);
        acc[0].z = fmaf(a0, w.z, acc[0].z); acc[0].w = fmaf(a0, w.w, acc[0].w);
        acc[1].x = fmaf(a1, w.x, acc[1].x); acc[1].y = fmaf(a1, w.y, acc[1].y);
        acc[1].z = fmaf(a1, w.z, acc[1].z); acc[1].w = fmaf(a1, w.w, acc[1].w);
        acc[2].x = fmaf(a2, w.x, acc[2].x); acc[2].y = fmaf(a2, w.y, acc[2].y);
        acc[2].z = fmaf(a2, w.z, acc[2].z); acc[2].w = fmaf(a2, w.w, acc[2].w);
        acc[3].x = fmaf(a3, w.x, acc[3].x); acc[3].y = fmaf(a3, w.y, acc[3].y);
        acc[3].z = fmaf(a3, w.z, acc[3].z); acc[3].w = fmaf(a3, w.w, acc[3].w);
    }
    __syncthreads();               // Ws/As dead; reuse Ws as the pooling slab

    float* slab = Ws;              // [64 graphs][64 cols]
    #pragma unroll
    for (int i = tid; i < 4096; i += 256) slab[i] = 0.f;
    __syncthreads();

    float4 bb = *(const float4*)(bias + col4);
    int curg = -1;
    float4 s4 = make_float4(0.f, 0.f, 0.f, 0.f);
    #pragma unroll
    for (int r = 0; r < 4; r++) {
        int row = base + rowq * 4 + r;
        if (row < n) {
            float4 p = *(const float4*)(jkacc + (size_t)row * 64 + col4);
            float4 vv;
            vv.x = fmaxf(acc[r].x + p.x + bb.x, 0.f);
            vv.y = fmaxf(acc[r].y + p.y + bb.y, 0.f);
            vv.z = fmaxf(acc[r].z + p.z + bb.z, 0.f);
            vv.w = fmaxf(acc[r].w + p.w + bb.w, 0.f);
            int g = batch[row];
            if (g != curg) {
                if (curg >= 0) {
                    atomicAdd(&slab[curg * 64 + col4 + 0], s4.x);
                    atomicAdd(&slab[curg * 64 + col4 + 1], s4.y);
                    atomicAdd(&slab[curg * 64 + col4 + 2], s4.z);
                    atomicAdd(&slab[curg * 64 + col4 + 3], s4.w);
                }
                curg = g; s4 = vv;
            } else {
                s4.x += vv.x; s4.y += vv.y; s4.z += vv.z; s4.w += vv.w;
            }
        }
    }
    if (curg >= 0) {
        atomicAdd(&slab[curg * 64 + col4 + 0], s4.x);
        atomicAdd(&slab[curg * 64 + col4 + 1], s4.y);
        atomicAdd(&slab[curg * 64 + col4 + 2], s4.z);
        atomicAdd(&slab[curg * 64 + col4 + 3], s4.w);
    }
    __syncthreads();

    int g0 = batch[base];
    int g1 = batch[(base + 63 < n) ? (base + 63) : (n - 1)];
    int cnt = (g1 - g0 + 1) * 64;
    for (int i = tid; i < cnt; i += 256) {
        int g = g0 + (i >> 6);
        int c = i & 63;
        float v = slab[g * 64 + c];
        if (v != 0.f) atomicAdd(&pooled[g * 64 + c], v);
    }
}

// ============ head ============
__global__ void k_head(
    const float* __restrict__ pooled,
    const float* __restrict__ W1, const float* __restrict__ b1,
    const float* __restrict__ W2, const float* __restrict__ b2,
    float* __restrict__ out)
{
    int g = threadIdx.x;
    float p[64];
    #pragma unroll
    for (int k = 0; k < 64; k++) p[k] = pooled[g * 64 + k];
    float h1[64];
    #pragma unroll
    for (int j = 0; j < 64; j++) {
        float acc = b1[j];
        #pragma unroll
        for (int k = 0; k < 64; k++) acc = fmaf(p[k], W1[k * 64 + j], acc);
        h1[j] = fmaxf(acc, 0.f);
    }
    float lg[10];
    float mx = -1e30f;
    #pragma unroll
    for (int c = 0; c < 10; c++) {
        float acc = b2[c];
        #pragma unroll
        for (int j = 0; j < 64; j++) acc = fmaf(h1[j], W2[j * 10 + c], acc);
        lg[c] = acc;
        mx = fmaxf(mx, acc);
    }
    float ssum = 0.f;
    #pragma unroll
    for (int c = 0; c < 10; c++) { lg[c] = __expf(lg[c] - mx); ssum += lg[c]; }
    float inv = 1.0f / ssum;
    #pragma unroll
    for (int c = 0; c < 10; c++) out[g * 10 + c] = lg[c] * inv;
}

extern "C" void kernel_launch(void* const* d_in, const int* in_sizes, int n_in,
                              void* d_out, int out_size, void* d_ws, size_t ws_size,
                              hipStream_t stream) {
    (void)in_sizes; (void)n_in; (void)out_size; (void)ws_size;
    const float* x     = (const float*)d_in[0];
    const int*   ei    = (const int*)d_in[1];
    const int*   batch = (const int*)d_in[2];
    const float* W0    = (const float*)d_in[3];
    const float* b0    = (const float*)d_in[4];
    const float* Wh    = (const float*)d_in[5];
    const float* bh    = (const float*)d_in[6];
    const float* jkW   = (const float*)d_in[7];   // [384][64] = 6 stacked [64][64]
    const float* jkb   = (const float*)d_in[8];
    const float* W1    = (const float*)d_in[9];
    const float* b1    = (const float*)d_in[10];
    const float* W2    = (const float*)d_in[11];
    const float* b2    = (const float*)d_in[12];

    const int* src = ei;
    const int* dst = ei + NE;

    float*          fws   = (float*)d_ws;
    float*          disq  = fws;                                     // 100352 f
    unsigned short* hWb   = (unsigned short*)(disq + 100352);        // NN*64 fp16 (12.8MB)
    float*          h     = (float*)(hWb + (size_t)NN * 64);         // NN*64 f
    float*          jkacc = h + (size_t)NN * 64;                     // NN*64 f
    float*          pooled= jkacc + (size_t)NN * 64;                 // 4096 f
    int*            counts= (int*)(pooled + 4096);                   // 100352
    int*            rowptr= counts + 100352;                         // NN+1
    int*            wptr  = rowptr + 100352;                         // 100352
    int*            bsum  = wptr + 100352;                           // 512
    int*            csr   = bsum + 512;                              // NE

    const int NB_N = (NN + 255) / 256;                               // 391
    const int NB_E = (NE + 255) / 256;                               // 3907

    // ---- CSR build ----
    hipMemsetAsync(counts, 0, (size_t)NN * sizeof(int), stream);
    k_hist<<<NB_E, 256, 0, stream>>>(dst, counts, NE);
    k_blocksum<<<NB_N, 256, 0, stream>>>(counts, bsum, NN);
    k_scanbsum<<<1, 512, 0, stream>>>(bsum, NB_N);
    k_scanwrite<<<NB_N, 256, 0, stream>>>(counts, bsum, rowptr, wptr, disq, NN, NE);
    k_scatter_part<<<NB_E * 8, 256, 0, stream>>>(src, dst, wptr, csr, NE);

    // ---- layers: GEMM_l (folds h_{l-1}'s JK block for l>=1) + gather ----
    const int gemm_grid   = (NN + 63) / 64;                          // 1563
    const int gather_grid = (NN + 3) / 4;                            // 25000
    for (int l = 0; l < NLAY; l++) {
        const float* A    = (l == 0) ? x : h;
        int          lda  = (l == 0) ? F_INF : HID;
        int          K    = (l == 0) ? F_INF : HID;
        const float* W    = (l == 0) ? W0 : (Wh + (size_t)(l - 1) * 64 * 64);
        const float* bias = (l == 0) ? b0 : (bh + (size_t)(l - 1) * 64);
        const float* jw   = (l == 0) ? nullptr : (jkW + (size_t)(l - 1) * 64 * 64);
        int          jkm  = (l == 0) ? 0 : ((l == 1) ? 1 : 2);

        k_gemm_dual<<<gemm_grid, 256, 0, stream>>>(A, lda, K, W, jw, disq,
                                                   hWb, jkacc, jkm, NN);
        k_gather<<<gather_grid, 256, 0, stream>>>(rowptr, csr, hWb, disq, bias, h, NN);
    }

    // ---- final: h5 @ jkW[5] + jkacc + jkb -> relu -> pool -> head ----
    hipMemsetAsync(pooled, 0, 64 * 64 * sizeof(float), stream);
    k_jkfin_pool<<<gemm_grid, 256, 0, stream>>>(h, jkW + (size_t)5 * 64 * 64, jkacc,
                                                jkb, batch, pooled, NN);
    k_head<<<1, 64, 0, stream>>>(pooled, W1, b1, W2, b2, (float*)d_out);
}

// Round 8
// 558.088 us; speedup vs baseline: 1.4993x; 1.0438x over previous
//
#include <hip/hip_runtime.h>
#include <hip/hip_fp16.h>

#define NN 100000
#define NE 1000000
#define F_INF 128
#define HID 64
#define NLAY 6
#define NCLS 10
#define NGRAPH 64
#define PART_SZ 12500   // NN/8 — contiguous node range per XCD partition

__device__ __forceinline__ float4 h4f(ushort4 u) {
    __half2 lo = *reinterpret_cast<__half2*>(&u);
    __half2 hi = *reinterpret_cast<__half2*>(reinterpret_cast<unsigned short*>(&u) + 2);
    float2 a = __half22float2(lo);
    float2 b = __half22float2(hi);
    return make_float4(a.x, a.y, b.x, b.y);
}

__device__ __forceinline__ ushort4 f4h(float4 v) {
    __half2 lo = __floats2half2_rn(v.x, v.y);
    __half2 hi = __floats2half2_rn(v.z, v.w);
    ushort4 u;
    *reinterpret_cast<__half2*>(&u) = lo;
    *reinterpret_cast<__half2*>(reinterpret_cast<unsigned short*>(&u) + 2) = hi;
    return u;
}

// ================= CSR build =================
__global__ void k_hist(const int* __restrict__ dst, int* __restrict__ counts, int e) {
    int i = blockIdx.x * 256 + threadIdx.x;
    if (i < e) atomicAdd(&counts[dst[i]], 1);
}

__global__ void k_blocksum(const int* __restrict__ counts, int* __restrict__ bsum, int n) {
    int i = blockIdx.x * 256 + threadIdx.x;
    int v = (i < n) ? counts[i] : 0;
    #pragma unroll
    for (int off = 32; off >= 1; off >>= 1) v += __shfl_down(v, off);
    __shared__ int ws[4];
    if ((threadIdx.x & 63) == 0) ws[threadIdx.x >> 6] = v;
    __syncthreads();
    if (threadIdx.x == 0) bsum[blockIdx.x] = ws[0] + ws[1] + ws[2] + ws[3];
}

__global__ void k_scanbsum(int* __restrict__ bsum, int nb) {   // 1 block, 512 thr
    __shared__ int sh[512];
    int t = threadIdx.x;
    int v = (t < nb) ? bsum[t] : 0;
    sh[t] = v; __syncthreads();
    for (int off = 1; off < 512; off <<= 1) {
        int x = (t >= off) ? sh[t - off] : 0;
        __syncthreads();
        sh[t] += x; __syncthreads();
    }
    if (t < nb) bsum[t] = sh[t] - v;   // exclusive
}

__global__ void k_scanwrite(const int* __restrict__ counts, const int* __restrict__ bsumx,
                            int* __restrict__ rowptr, int* __restrict__ wptr,
                            float* __restrict__ disq, int n, int e) {
    __shared__ int sh[256];
    int t = threadIdx.x;
    int i = blockIdx.x * 256 + t;
    int v = (i < n) ? counts[i] : 0;
    sh[t] = v; __syncthreads();
    for (int off = 1; off < 256; off <<= 1) {
        int x = (t >= off) ? sh[t - off] : 0;
        __syncthreads();
        sh[t] += x; __syncthreads();
    }
    int excl = sh[t] - v + bsumx[blockIdx.x];
    if (i < n) {
        rowptr[i] = excl;
        wptr[i]   = excl;
        disq[i]   = rsqrtf((float)(v + 1));   // +1 self-loop
    }
    if (i == 0) rowptr[n] = e;
}

// XCD-partitioned scatter (R6-verified): stores to a csr line issue from one XCD
__global__ void k_scatter_part(const int* __restrict__ src, const int* __restrict__ dst,
                               int* __restrict__ wptr, int* __restrict__ csr, int e) {
    int part = blockIdx.x & 7;
    int i = (blockIdx.x >> 3) * 256 + threadIdx.x;
    if (i < e) {
        int d = dst[i];
        if (d / PART_SZ == part) {
            int pos = atomicAdd(&wptr[d], 1);
            csr[pos] = src[i];
        }
    }
}

// ============ dual GEMM: C16 = fp16((A@W)*disq[row]); optionally jkacc (+)= A@jkw ============
__global__ __launch_bounds__(256) void k_gemm_dual(
    const float* __restrict__ A, int lda, int K,
    const float* __restrict__ W,
    const float* __restrict__ jkw,
    const float* __restrict__ disq,
    unsigned short* __restrict__ C16,    // [n][64] fp16
    float* __restrict__ jkacc,           // [n][64] fp32
    int jk_mode, int n)
{
    __shared__ float Ws[64 * 64];
    __shared__ float Ws2[64 * 64];
    __shared__ float As[64 * 68];
    const int tid  = threadIdx.x;
    const int col4 = (tid & 15) * 4;
    const int rowq = tid >> 4;
    const int base = blockIdx.x * 64;

    {
        #pragma unroll
        for (int i = 0; i < 4; i++) {
            float4 v = *(const float4*)(W + (size_t)(i * 256 + tid) * 4);
            *(float4*)(Ws + (size_t)(i * 256 + tid) * 4) = v;
        }
        if (jk_mode) {
            #pragma unroll
            for (int i = 0; i < 4; i++) {
                float4 v = *(const float4*)(jkw + (size_t)(i * 256 + tid) * 4);
                *(float4*)(Ws2 + (size_t)(i * 256 + tid) * 4) = v;
            }
        }
        #pragma unroll
        for (int rr = 0; rr < 4; rr++) {
            int row = base + rowq + rr * 16;
            float4 v = make_float4(0.f, 0.f, 0.f, 0.f);
            if (row < n) v = *(const float4*)(A + (size_t)row * lda + col4);
            *(float4*)(As + (size_t)(rowq + rr * 16) * 68 + col4) = v;
        }
    }
    __syncthreads();

    float4 acc[4], acc2[4];
    #pragma unroll
    for (int r = 0; r < 4; r++) {
        acc[r]  = make_float4(0.f, 0.f, 0.f, 0.f);
        acc2[r] = make_float4(0.f, 0.f, 0.f, 0.f);
    }

    for (int k0 = 0; k0 < K; k0 += 64) {
        const bool more = (k0 + 64) < K;
        float4 wreg[4], areg[4];
        if (more) {
            #pragma unroll
            for (int i = 0; i < 4; i++)
                wreg[i] = *(const float4*)(W + (size_t)(k0 + 64) * 64 + (i * 256 + tid) * 4);
            #pragma unroll
            for (int rr = 0; rr < 4; rr++) {
                int row = base + rowq + rr * 16;
                areg[rr] = make_float4(0.f, 0.f, 0.f, 0.f);
                if (row < n) areg[rr] = *(const float4*)(A + (size_t)row * lda + k0 + 64 + col4);
            }
        }
        if (jk_mode && k0 == 0) {
            #pragma unroll 4
            for (int k = 0; k < 64; k++) {
                float4 w  = *(const float4*)(Ws  + k * 64 + col4);
                float4 w2 = *(const float4*)(Ws2 + k * 64 + col4);
                float a0 = As[(rowq * 4 + 0) * 68 + k];
                float a1 = As[(rowq * 4 + 1) * 68 + k];
                float a2 = As[(rowq * 4 + 2) * 68 + k];
                float a3 = As[(rowq * 4 + 3) * 68 + k];
                acc[0].x = fmaf(a0, w.x, acc[0].x); acc[0].y = fmaf(a0, w.y, acc[0].y);
                acc[0].z = fmaf(a0, w.z, acc[0].z); acc[0].w = fmaf(a0, w.w, acc[0].w);
                acc[1].x = fmaf(a1, w.x, acc[1].x); acc[1].y = fmaf(a1, w.y, acc[1].y);
                acc[1].z = fmaf(a1, w.z, acc[1].z); acc[1].w = fmaf(a1, w.w, acc[1].w);
                acc[2].x = fmaf(a2, w.x, acc[2].x); acc[2].y = fmaf(a2, w.y, acc[2].y);
                acc[2].z = fmaf(a2, w.z, acc[2].z); acc[2].w = fmaf(a2, w.w, acc[2].w);
                acc[3].x = fmaf(a3, w.x, acc[3].x); acc[3].y = fmaf(a3, w.y, acc[3].y);
                acc[3].z = fmaf(a3, w.z, acc[3].z); acc[3].w = fmaf(a3, w.w, acc[3].w);
                acc2[0].x = fmaf(a0, w2.x, acc2[0].x); acc2[0].y = fmaf(a0, w2.y, acc2[0].y);
                acc2[0].z = fmaf(a0, w2.z, acc2[0].z); acc2[0].w = fmaf(a0, w2.w, acc2[0].w);
                acc2[1].x = fmaf(a1, w2.x, acc2[1].x); acc2[1].y = fmaf(a1, w2.y, acc2[1].y);
                acc2[1].z = fmaf(a1, w2.z, acc2[1].z); acc2[1].w = fmaf(a1, w2.w, acc2[1].w);
                acc2[2].x = fmaf(a2, w2.x, acc2[2].x); acc2[2].y = fmaf(a2, w2.y, acc2[2].y);
                acc2[2].z = fmaf(a2, w2.z, acc2[2].z); acc2[2].w = fmaf(a2, w2.w, acc2[2].w);
                acc2[3].x = fmaf(a3, w2.x, acc2[3].x); acc2[3].y = fmaf(a3, w2.y, acc2[3].y);
                acc2[3].z = fmaf(a3, w2.z, acc2[3].z); acc2[3].w = fmaf(a3, w2.w, acc2[3].w);
            }
        } else {
            #pragma unroll 8
            for (int k = 0; k < 64; k++) {
                float4 w = *(const float4*)(Ws + k * 64 + col4);
                float a0 = As[(rowq * 4 + 0) * 68 + k];
                float a1 = As[(rowq * 4 + 1) * 68 + k];
                float a2 = As[(rowq * 4 + 2) * 68 + k];
                float a3 = As[(rowq * 4 + 3) * 68 + k];
                acc[0].x = fmaf(a0, w.x, acc[0].x); acc[0].y = fmaf(a0, w.y, acc[0].y);
                acc[0].z = fmaf(a0, w.z, acc[0].z); acc[0].w = fmaf(a0, w.w, acc[0].w);
                acc[1].x = fmaf(a1, w.x, acc[1].x); acc[1].y = fmaf(a1, w.y, acc[1].y);
                acc[1].z = fmaf(a1, w.z, acc[1].z); acc[1].w = fmaf(a1, w.w, acc[1].w);
                acc[2].x = fmaf(a2, w.x, acc[2].x); acc[2].y = fmaf(a2, w.y, acc[2].y);
                acc[2].z = fmaf(a2, w.z, acc[2].z); acc[2].w = fmaf(a2, w.w, acc[2].w);
                acc[3].x = fmaf(a3, w.x, acc[3].x); acc[3].y = fmaf(a3, w.y, acc[3].y);
                acc[3].z = fmaf(a3, w.z, acc[3].z); acc[3].w = fmaf(a3, w.w, acc[3].w);
            }
        }
        __syncthreads();
        if (more) {
            #pragma unroll
            for (int i = 0; i < 4; i++)
                *(float4*)(Ws + (size_t)(i * 256 + tid) * 4) = wreg[i];
            #pragma unroll
            for (int rr = 0; rr < 4; rr++)
                *(float4*)(As + (size_t)(rowq + rr * 16) * 68 + col4) = areg[rr];
            __syncthreads();
        }
    }

    #pragma unroll
    for (int r = 0; r < 4; r++) {
        int row = base + rowq * 4 + r;
        if (row < n) {
            float s = disq[row];
            float4 o;
            o.x = acc[r].x * s; o.y = acc[r].y * s;
            o.z = acc[r].z * s; o.w = acc[r].w * s;
            ((ushort4*)C16)[(size_t)row * 16 + (tid & 15)] = f4h(o);
            if (jk_mode == 1) {
                *(float4*)(jkacc + (size_t)row * 64 + col4) = acc2[r];
            } else if (jk_mode == 2) {
                float4 p = *(const float4*)(jkacc + (size_t)row * 64 + col4);
                p.x += acc2[r].x; p.y += acc2[r].y;
                p.z += acc2[r].z; p.w += acc2[r].w;
                *(float4*)(jkacc + (size_t)row * 64 + col4) = p;
            }
        }
    }
}

// ============ gather: wave per node, fp16 input, 16 lanes x 8B, 4 edge slots ============
__global__ __launch_bounds__(256) void k_gather(
    const int* __restrict__ rowptr, const int* __restrict__ csr,
    const unsigned short* __restrict__ hW16, const float* __restrict__ disq,
    const float* __restrict__ bias, float* __restrict__ hout, int n)
{
    const ushort4* hW4 = (const ushort4*)hW16;
    int wid  = (blockIdx.x * 256 + threadIdx.x) >> 6;
    if (wid >= n) return;
    int lane = threadIdx.x & 63;
    int fb = lane & 15;       // 8B chunk index within 128B row
    int es = lane >> 4;       // edge slot 0..3
    int j  = rowptr[wid];
    int r1 = rowptr[wid + 1];
    float4 v  = make_float4(0.f, 0.f, 0.f, 0.f);
    float4 v2 = make_float4(0.f, 0.f, 0.f, 0.f);
    if (es == 0) v = h4f(hW4[(size_t)wid * 16 + fb]);    // self-loop
    while (j < r1) {
        int cnt = min(r1 - j, 64);
        int idx = (lane < cnt) ? csr[j + lane] : 0;
        int jj = 0;
        for (; jj + 8 <= cnt; jj += 8) {
            int s0 = __shfl(idx, jj + es);
            int s1 = __shfl(idx, jj + 4 + es);
            float4 t0 = h4f(hW4[(size_t)s0 * 16 + fb]);
            float4 t1 = h4f(hW4[(size_t)s1 * 16 + fb]);
            v.x  += t0.x; v.y  += t0.y; v.z  += t0.z; v.w  += t0.w;
            v2.x += t1.x; v2.y += t1.y; v2.z += t1.z; v2.w += t1.w;
        }
        for (; jj < cnt; jj += 4) {
            int sidx = jj + es;
            int s = __shfl(idx, (sidx < cnt) ? sidx : 0);
            if (sidx < cnt) {
                float4 t = h4f(hW4[(size_t)s * 16 + fb]);
                v.x += t.x; v.y += t.y; v.z += t.z; v.w += t.w;
            }
        }
        j += cnt;
    }
    v.x += v2.x; v.y += v2.y; v.z += v2.z; v.w += v2.w;
    v.x += __shfl_xor(v.x, 16); v.y += __shfl_xor(v.y, 16);
    v.z += __shfl_xor(v.z, 16); v.w += __shfl_xor(v.w, 16);
    v.x += __shfl_xor(v.x, 32); v.y += __shfl_xor(v.y, 32);
    v.z += __shfl_xor(v.z, 32); v.w += __shfl_xor(v.w, 32);
    if (es == 0) {
        float s = disq[wid];
        float4 b = ((const float4*)bias)[fb];
        float4 o;
        o.x = fmaxf(fmaf(s, v.x, b.x), 0.f);
        o.y = fmaxf(fmaf(s, v.y, b.y), 0.f);
        o.z = fmaxf(fmaf(s, v.z, b.z), 0.f);
        o.w = fmaxf(fmaf(s, v.w, b.w), 0.f);
        ((float4*)hout)[(size_t)wid * 16 + fb] = o;
    }
}

// ============ final: t = relu(h@jkW5 + jkacc + jkb); pool by batch (LDS pre-reduce) ============
__global__ __launch_bounds__(256) void k_jkfin_pool(
    const float* __restrict__ A,
    const float* __restrict__ W,
    const float* __restrict__ jkacc,
    const float* __restrict__ bias,
    const int* __restrict__ batch,
    float* __restrict__ pooled,
    int n)
{
    __shared__ float Ws[64 * 64];
    __shared__ float As[64 * 68];
    const int tid  = threadIdx.x;
    const int col4 = (tid & 15) * 4;
    const int rowq = tid >> 4;
    const int base = blockIdx.x * 64;

    #pragma unroll
    for (int i = 0; i < 4; i++) {
        float4 v = *(const float4*)(W + (size_t)(i * 256 + tid) * 4);
        *(float4*)(Ws + (size_t)(i * 256 + tid) * 4) = v;
    }
    #pragma unroll
    for (int rr = 0; rr < 4; rr++) {
        int row = base + rowq + rr * 16;
        float4 v = make_float4(0.f, 0.f, 0.f, 0.f);
        if (row < n) v = *(const float4*)(A + (size_t)row * 64 + col4);
        *(float4*)(As + (size_t)(rowq + rr * 16) * 68 + col4) = v;
    }
    __syncthreads();

    float4 acc[4];
    #pragma unroll
    for (int r = 0; r < 4; r++) acc[r] = make_float4(0.f, 0.f, 0.f, 0.f);
    #pragma unroll 8
    for (int k = 0; k < 64; k++) {
        float4 w = *(const float4*)(Ws + k * 64 + col4);
        float a0 = As[(rowq * 4 + 0) * 68 + k];
        float a1 = As[(rowq * 4 + 1) * 68 + k];
        float a2 = As[(rowq * 4 + 2) * 68 + k];
        float a3 = As[(rowq * 4 + 3) * 68 + k];
        acc[0].x = fmaf(a0, w.x, acc[0].x); acc[0].y = fmaf(a0, w.y, acc[0].y);
        acc[0].z = fmaf(a0, w.z, acc[0].z); acc[0].w = fmaf(a0, w.w, acc[0].w);
        acc[1].x = fmaf(a1, w.x, acc[1].x); acc[1].y = fmaf(a1, w.y, acc[1].y);
        acc[1].z = fmaf(a1, w.z, acc[1].z); acc[1].w = fmaf(a1, w.w, acc[1].w);
        acc[2].x = fmaf(a2, w.x, acc[2].x); acc[2].y = fmaf(a2, w.y, acc[2].y);
        acc[2].z = fmaf(a2, w.z, acc[2].z); acc[2].w = fmaf(a2, w.w, acc[2].w);
        acc[3].x = fmaf(a3, w.x, acc[3].x); acc[3].y = fmaf(a3, w.y, acc[3].y);
        acc[3].z = fmaf(a3, w.z, acc[3].z); acc[3].w = fmaf(a3, w.w, acc[3].w);
    }
    __syncthreads();               // Ws/As dead; reuse Ws as the pooling slab

    float* slab = Ws;              // [64 graphs][64 cols]
    #pragma unroll
    for (int i = tid; i < 4096; i += 256) slab[i] = 0.f;
    __syncthreads();

    float4 bb = *(const float4*)(bias + col4);
    int curg = -1;
    float4 s4 = make_float4(0.f, 0.f, 0.f, 0.f);
    #pragma unroll
    for (int r = 0; r < 4; r++) {
        int row = base + rowq * 4 + r;
        if (row < n) {
            float4 p = *(const float4*)(jkacc + (size_t)row * 64 + col4);
            float4 vv;
            vv.x = fmaxf(acc[r].x + p.x + bb.x, 0.f);
            vv.y = fmaxf(acc[r].y + p.y + bb.y, 0.f);
            vv.z = fmaxf(acc[r].z + p.z + bb.z, 0.f);
            vv.w = fmaxf(acc[r].w + p.w + bb.w, 0.f);
            int g = batch[row];
            if (g != curg) {
                if (curg >= 0) {
                    atomicAdd(&slab[curg * 64 + col4 + 0], s4.x);
                    atomicAdd(&slab[curg * 64 + col4 + 1], s4.y);
                    atomicAdd(&slab[curg * 64 + col4 + 2], s4.z);
                    atomicAdd(&slab[curg * 64 + col4 + 3], s4.w);
                }
                curg = g; s4 = vv;
            } else {
                s4.x += vv.x; s4.y += vv.y; s4.z += vv.z; s4.w += vv.w;
            }
        }
    }
    if (curg >= 0) {
        atomicAdd(&slab[curg * 64 + col4 + 0], s4.x);
        atomicAdd(&slab[curg * 64 + col4 + 1], s4.y);
        atomicAdd(&slab[curg * 64 + col4 + 2], s4.z);
        atomicAdd(&slab[curg * 64 + col4 + 3], s4.w);
    }
    __syncthreads();

    int g0 = batch[base];
    int g1 = batch[(base + 63 < n) ? (base + 63) : (n - 1)];
    int cnt = (g1 - g0 + 1) * 64;
    for (int i = tid; i < cnt; i += 256) {
        int g = g0 + (i >> 6);
        int c = i & 63;
        float v = slab[g * 64 + c];
        if (v != 0.f) atomicAdd(&pooled[g * 64 + c], v);
    }
}

// ============ head: one block per graph, LDS-staged, no register spill ============
__global__ __launch_bounds__(64) void k_head(
    const float* __restrict__ pooled,
    const float* __restrict__ W1, const float* __restrict__ b1,
    const float* __restrict__ W2, const float* __restrict__ b2,
    float* __restrict__ out)
{
    __shared__ float p[64];
    __shared__ float h1[64];
    __shared__ float lg[16];
    const int g = blockIdx.x;      // graph
    const int t = threadIdx.x;     // 64 threads

    p[t] = pooled[g * 64 + t];
    __syncthreads();

    // h1[t] = relu(b1[t] + sum_k p[k] * W1[k][t]) — W1 reads coalesced across t
    float acc = b1[t];
    #pragma unroll 8
    for (int k = 0; k < 64; k++) acc = fmaf(p[k], W1[k * 64 + t], acc);
    h1[t] = fmaxf(acc, 0.f);
    __syncthreads();

    // logits: threads 0..9
    if (t < NCLS) {
        float a = b2[t];
        #pragma unroll 8
        for (int j = 0; j < 64; j++) a = fmaf(h1[j], W2[j * NCLS + t], a);
        lg[t] = a;
    }
    __syncthreads();

    if (t == 0) {
        float mx = lg[0];
        #pragma unroll
        for (int c = 1; c < NCLS; c++) mx = fmaxf(mx, lg[c]);
        float ssum = 0.f;
        float e[NCLS];
        #pragma unroll
        for (int c = 0; c < NCLS; c++) { e[c] = __expf(lg[c] - mx); ssum += e[c]; }
        float inv = 1.0f / ssum;
        #pragma unroll
        for (int c = 0; c < NCLS; c++) out[g * NCLS + c] = e[c] * inv;
    }
}

extern "C" void kernel_launch(void* const* d_in, const int* in_sizes, int n_in,
                              void* d_out, int out_size, void* d_ws, size_t ws_size,
                              hipStream_t stream) {
    (void)in_sizes; (void)n_in; (void)out_size; (void)ws_size;
    const float* x     = (const float*)d_in[0];
    const int*   ei    = (const int*)d_in[1];
    const int*   batch = (const int*)d_in[2];
    const float* W0    = (const float*)d_in[3];
    const float* b0    = (const float*)d_in[4];
    const float* Wh    = (const float*)d_in[5];
    const float* bh    = (const float*)d_in[6];
    const float* jkW   = (const float*)d_in[7];   // [384][64] = 6 stacked [64][64]
    const float* jkb   = (const float*)d_in[8];
    const float* W1    = (const float*)d_in[9];
    const float* b1    = (const float*)d_in[10];
    const float* W2    = (const float*)d_in[11];
    const float* b2    = (const float*)d_in[12];

    const int* src = ei;
    const int* dst = ei + NE;

    float*          fws   = (float*)d_ws;
    float*          disq  = fws;                                     // 100352 f
    unsigned short* hWb   = (unsigned short*)(disq + 100352);        // NN*64 fp16 (12.8MB)
    float*          h     = (float*)(hWb + (size_t)NN * 64);         // NN*64 f
    float*          jkacc = h + (size_t)NN * 64;                     // NN*64 f
    float*          pooled= jkacc + (size_t)NN * 64;                 // 4096 f
    int*            counts= (int*)(pooled + 4096);                   // 100352
    int*            rowptr= counts + 100352;                         // NN+1
    int*            wptr  = rowptr + 100352;                         // 100352
    int*            bsum  = wptr + 100352;                           // 512
    int*            csr   = bsum + 512;                              // NE

    const int NB_N = (NN + 255) / 256;                               // 391
    const int NB_E = (NE + 255) / 256;                               // 3907

    // ---- CSR build ----
    hipMemsetAsync(counts, 0, (size_t)NN * sizeof(int), stream);
    k_hist<<<NB_E, 256, 0, stream>>>(dst, counts, NE);
    k_blocksum<<<NB_N, 256, 0, stream>>>(counts, bsum, NN);
    k_scanbsum<<<1, 512, 0, stream>>>(bsum, NB_N);
    k_scanwrite<<<NB_N, 256, 0, stream>>>(counts, bsum, rowptr, wptr, disq, NN, NE);
    k_scatter_part<<<NB_E * 8, 256, 0, stream>>>(src, dst, wptr, csr, NE);

    // ---- layers: GEMM_l (folds h_{l-1}'s JK block for l>=1) + gather ----
    const int gemm_grid   = (NN + 63) / 64;                          // 1563
    const int gather_grid = (NN + 3) / 4;                            // 25000
    for (int l = 0; l < NLAY; l++) {
        const float* A    = (l == 0) ? x : h;
        int          lda  = (l == 0) ? F_INF : HID;
        int          K    = (l == 0) ? F_INF : HID;
        const float* W    = (l == 0) ? W0 : (Wh + (size_t)(l - 1) * 64 * 64);
        const float* bias = (l == 0) ? b0 : (bh + (size_t)(l - 1) * 64);
        const float* jw   = (l == 0) ? nullptr : (jkW + (size_t)(l - 1) * 64 * 64);
        int          jkm  = (l == 0) ? 0 : ((l == 1) ? 1 : 2);

        k_gemm_dual<<<gemm_grid, 256, 0, stream>>>(A, lda, K, W, jw, disq,
                                                   hWb, jkacc, jkm, NN);
        k_gather<<<gather_grid, 256, 0, stream>>>(rowptr, csr, hWb, disq, bias, h, NN);
    }

    // ---- final: h5 @ jkW[5] + jkacc + jkb -> relu -> pool -> head ----
    hipMemsetAsync(pooled, 0, 64 * 64 * sizeof(float), stream);
    k_jkfin_pool<<<gemm_grid, 256, 0, stream>>>(h, jkW + (size_t)5 * 64 * 64, jkacc,
                                                jkb, batch, pooled, NN);
    k_head<<<NGRAPH, 64, 0, stream>>>(pooled, W1, b1, W2, b2, (float*)d_out);
}

// Round 9
// 550.723 us; speedup vs baseline: 1.5193x; 1.0134x over previous
//
#include <hip/hip_runtime.h>
#include <hip/hip_fp16.h>

#define NN 100000
#define NE 1000000
#define F_INF 128
#define HID 64
#define NLAY 6
#define NCLS 10
#define NGRAPH 64
#define PART_SZ 12500   // NN/8 — contiguous node range per XCD partition

__device__ __forceinline__ float4 h4f(ushort4 u) {
    __half2 lo = *reinterpret_cast<__half2*>(&u);
    __half2 hi = *reinterpret_cast<__half2*>(reinterpret_cast<unsigned short*>(&u) + 2);
    float2 a = __half22float2(lo);
    float2 b = __half22float2(hi);
    return make_float4(a.x, a.y, b.x, b.y);
}

__device__ __forceinline__ ushort4 f4h(float4 v) {
    __half2 lo = __floats2half2_rn(v.x, v.y);
    __half2 hi = __floats2half2_rn(v.z, v.w);
    ushort4 u;
    *reinterpret_cast<__half2*>(&u) = lo;
    *reinterpret_cast<__half2*>(reinterpret_cast<unsigned short*>(&u) + 2) = hi;
    return u;
}

// ================= CSR build =================
__global__ void k_hist(const int* __restrict__ dst, int* __restrict__ counts, int e) {
    int i = blockIdx.x * 256 + threadIdx.x;
    if (i < e) atomicAdd(&counts[dst[i]], 1);
}

__global__ void k_blocksum(const int* __restrict__ counts, int* __restrict__ bsum, int n) {
    int i = blockIdx.x * 256 + threadIdx.x;
    int v = (i < n) ? counts[i] : 0;
    #pragma unroll
    for (int off = 32; off >= 1; off >>= 1) v += __shfl_down(v, off);
    __shared__ int ws[4];
    if ((threadIdx.x & 63) == 0) ws[threadIdx.x >> 6] = v;
    __syncthreads();
    if (threadIdx.x == 0) bsum[blockIdx.x] = ws[0] + ws[1] + ws[2] + ws[3];
}

__global__ void k_scanbsum(int* __restrict__ bsum, int nb) {   // 1 block, 512 thr
    __shared__ int sh[512];
    int t = threadIdx.x;
    int v = (t < nb) ? bsum[t] : 0;
    sh[t] = v; __syncthreads();
    for (int off = 1; off < 512; off <<= 1) {
        int x = (t >= off) ? sh[t - off] : 0;
        __syncthreads();
        sh[t] += x; __syncthreads();
    }
    if (t < nb) bsum[t] = sh[t] - v;   // exclusive
}

__global__ void k_scanwrite(const int* __restrict__ counts, const int* __restrict__ bsumx,
                            int* __restrict__ rowptr, int* __restrict__ wptr,
                            float* __restrict__ disq, int n, int e) {
    __shared__ int sh[256];
    int t = threadIdx.x;
    int i = blockIdx.x * 256 + t;
    int v = (i < n) ? counts[i] : 0;
    sh[t] = v; __syncthreads();
    for (int off = 1; off < 256; off <<= 1) {
        int x = (t >= off) ? sh[t - off] : 0;
        __syncthreads();
        sh[t] += x; __syncthreads();
    }
    int excl = sh[t] - v + bsumx[blockIdx.x];
    if (i < n) {
        rowptr[i] = excl;
        wptr[i]   = excl;
        disq[i]   = rsqrtf((float)(v + 1));   // +1 self-loop
    }
    if (i == 0) rowptr[n] = e;
}

// XCD-partitioned scatter (R6-verified): stores to a csr line issue from one XCD
__global__ void k_scatter_part(const int* __restrict__ src, const int* __restrict__ dst,
                               int* __restrict__ wptr, int* __restrict__ csr, int e) {
    int part = blockIdx.x & 7;
    int i = (blockIdx.x >> 3) * 256 + threadIdx.x;
    if (i < e) {
        int d = dst[i];
        if (d / PART_SZ == part) {
            int pos = atomicAdd(&wptr[d], 1);
            csr[pos] = src[i];
        }
    }
}

// ============ dual GEMM: C16 = fp16((A@W)*disq[row]); optionally jkacc (+)= A@jkw ============
// a16: A is fp16 [n][64] (layers 1-5, K==64). Else A fp32 [n][lda].
__global__ __launch_bounds__(256) void k_gemm_dual(
    const void* __restrict__ Araw, int lda, int K,
    const float* __restrict__ W,
    const float* __restrict__ jkw,
    const float* __restrict__ disq,
    unsigned short* __restrict__ C16,    // [n][64] fp16
    float* __restrict__ jkacc,           // [n][64] fp32
    int jk_mode, int a16, int n)
{
    __shared__ float Ws[64 * 64];
    __shared__ float Ws2[64 * 64];
    __shared__ float As[64 * 68];
    const int tid  = threadIdx.x;
    const int col4 = (tid & 15) * 4;
    const int rowq = tid >> 4;
    const int base = blockIdx.x * 64;

    {
        #pragma unroll
        for (int i = 0; i < 4; i++) {
            float4 v = *(const float4*)(W + (size_t)(i * 256 + tid) * 4);
            *(float4*)(Ws + (size_t)(i * 256 + tid) * 4) = v;
        }
        if (jk_mode) {
            #pragma unroll
            for (int i = 0; i < 4; i++) {
                float4 v = *(const float4*)(jkw + (size_t)(i * 256 + tid) * 4);
                *(float4*)(Ws2 + (size_t)(i * 256 + tid) * 4) = v;
            }
        }
        if (a16) {
            const ushort4* Ah = (const ushort4*)Araw;
            #pragma unroll
            for (int rr = 0; rr < 4; rr++) {
                int row = base + rowq + rr * 16;
                float4 v = make_float4(0.f, 0.f, 0.f, 0.f);
                if (row < n) v = h4f(Ah[(size_t)row * 16 + (tid & 15)]);
                *(float4*)(As + (size_t)(rowq + rr * 16) * 68 + col4) = v;
            }
        } else {
            const float* Af = (const float*)Araw;
            #pragma unroll
            for (int rr = 0; rr < 4; rr++) {
                int row = base + rowq + rr * 16;
                float4 v = make_float4(0.f, 0.f, 0.f, 0.f);
                if (row < n) v = *(const float4*)(Af + (size_t)row * lda + col4);
                *(float4*)(As + (size_t)(rowq + rr * 16) * 68 + col4) = v;
            }
        }
    }
    __syncthreads();

    float4 acc[4], acc2[4];
    #pragma unroll
    for (int r = 0; r < 4; r++) {
        acc[r]  = make_float4(0.f, 0.f, 0.f, 0.f);
        acc2[r] = make_float4(0.f, 0.f, 0.f, 0.f);
    }

    for (int k0 = 0; k0 < K; k0 += 64) {
        const bool more = (k0 + 64) < K;    // only layer 0 (fp32, K=128)
        float4 wreg[4], areg[4];
        if (more) {
            const float* Af = (const float*)Araw;
            #pragma unroll
            for (int i = 0; i < 4; i++)
                wreg[i] = *(const float4*)(W + (size_t)(k0 + 64) * 64 + (i * 256 + tid) * 4);
            #pragma unroll
            for (int rr = 0; rr < 4; rr++) {
                int row = base + rowq + rr * 16;
                areg[rr] = make_float4(0.f, 0.f, 0.f, 0.f);
                if (row < n) areg[rr] = *(const float4*)(Af + (size_t)row * lda + k0 + 64 + col4);
            }
        }
        if (jk_mode && k0 == 0) {
            #pragma unroll 4
            for (int k = 0; k < 64; k++) {
                float4 w  = *(const float4*)(Ws  + k * 64 + col4);
                float4 w2 = *(const float4*)(Ws2 + k * 64 + col4);
                float a0 = As[(rowq * 4 + 0) * 68 + k];
                float a1 = As[(rowq * 4 + 1) * 68 + k];
                float a2 = As[(rowq * 4 + 2) * 68 + k];
                float a3 = As[(rowq * 4 + 3) * 68 + k];
                acc[0].x = fmaf(a0, w.x, acc[0].x); acc[0].y = fmaf(a0, w.y, acc[0].y);
                acc[0].z = fmaf(a0, w.z, acc[0].z); acc[0].w = fmaf(a0, w.w, acc[0].w);
                acc[1].x = fmaf(a1, w.x, acc[1].x); acc[1].y = fmaf(a1, w.y, acc[1].y);
                acc[1].z = fmaf(a1, w.z, acc[1].z); acc[1].w = fmaf(a1, w.w, acc[1].w);
                acc[2].x = fmaf(a2, w.x, acc[2].x); acc[2].y = fmaf(a2, w.y, acc[2].y);
                acc[2].z = fmaf(a2, w.z, acc[2].z); acc[2].w = fmaf(a2, w.w, acc[2].w);
                acc[3].x = fmaf(a3, w.x, acc[3].x); acc[3].y = fmaf(a3, w.y, acc[3].y);
                acc[3].z = fmaf(a3, w.z, acc[3].z); acc[3].w = fmaf(a3, w.w, acc[3].w);
                acc2[0].x = fmaf(a0, w2.x, acc2[0].x); acc2[0].y = fmaf(a0, w2.y, acc2[0].y);
                acc2[0].z = fmaf(a0, w2.z, acc2[0].z); acc2[0].w = fmaf(a0, w2.w, acc2[0].w);
                acc2[1].x = fmaf(a1, w2.x, acc2[1].x); acc2[1].y = fmaf(a1, w2.y, acc2[1].y);
                acc2[1].z = fmaf(a1, w2.z, acc2[1].z); acc2[1].w = fmaf(a1, w2.w, acc2[1].w);
                acc2[2].x = fmaf(a2, w2.x, acc2[2].x); acc2[2].y = fmaf(a2, w2.y, acc2[2].y);
                acc2[2].z = fmaf(a2, w2.z, acc2[2].z); acc2[2].w = fmaf(a2, w2.w, acc2[2].w);
                acc2[3].x = fmaf(a3, w2.x, acc2[3].x); acc2[3].y = fmaf(a3, w2.y, acc2[3].y);
                acc2[3].z = fmaf(a3, w2.z, acc2[3].z); acc2[3].w = fmaf(a3, w2.w, acc2[3].w);
            }
        } else {
            #pragma unroll 8
            for (int k = 0; k < 64; k++) {
                float4 w = *(const float4*)(Ws + k * 64 + col4);
                float a0 = As[(rowq * 4 + 0) * 68 + k];
                float a1 = As[(rowq * 4 + 1) * 68 + k];
                float a2 = As[(rowq * 4 + 2) * 68 + k];
                float a3 = As[(rowq * 4 + 3) * 68 + k];
                acc[0].x = fmaf(a0, w.x, acc[0].x); acc[0].y = fmaf(a0, w.y, acc[0].y);
                acc[0].z = fmaf(a0, w.z, acc[0].z); acc[0].w = fmaf(a0, w.w, acc[0].w);
                acc[1].x = fmaf(a1, w.x, acc[1].x); acc[1].y = fmaf(a1, w.y, acc[1].y);
                acc[1].z = fmaf(a1, w.z, acc[1].z); acc[1].w = fmaf(a1, w.w, acc[1].w);
                acc[2].x = fmaf(a2, w.x, acc[2].x); acc[2].y = fmaf(a2, w.y, acc[2].y);
                acc[2].z = fmaf(a2, w.z, acc[2].z); acc[2].w = fmaf(a2, w.w, acc[2].w);
                acc[3].x = fmaf(a3, w.x, acc[3].x); acc[3].y = fmaf(a3, w.y, acc[3].y);
                acc[3].z = fmaf(a3, w.z, acc[3].z); acc[3].w = fmaf(a3, w.w, acc[3].w);
            }
        }
        __syncthreads();
        if (more) {
            #pragma unroll
            for (int i = 0; i < 4; i++)
                *(float4*)(Ws + (size_t)(i * 256 + tid) * 4) = wreg[i];
            #pragma unroll
            for (int rr = 0; rr < 4; rr++)
                *(float4*)(As + (size_t)(rowq + rr * 16) * 68 + col4) = areg[rr];
            __syncthreads();
        }
    }

    #pragma unroll
    for (int r = 0; r < 4; r++) {
        int row = base + rowq * 4 + r;
        if (row < n) {
            float s = disq[row];
            float4 o;
            o.x = acc[r].x * s; o.y = acc[r].y * s;
            o.z = acc[r].z * s; o.w = acc[r].w * s;
            ((ushort4*)C16)[(size_t)row * 16 + (tid & 15)] = f4h(o);
            if (jk_mode == 1) {
                *(float4*)(jkacc + (size_t)row * 64 + col4) = acc2[r];
            } else if (jk_mode == 2) {
                float4 p = *(const float4*)(jkacc + (size_t)row * 64 + col4);
                p.x += acc2[r].x; p.y += acc2[r].y;
                p.z += acc2[r].z; p.w += acc2[r].w;
                *(float4*)(jkacc + (size_t)row * 64 + col4) = p;
            }
        }
    }
}

// ============ gather: wave per node, fp16 in/out, 16 edges per step (4 loads in flight) ============
__global__ __launch_bounds__(256) void k_gather(
    const int* __restrict__ rowptr, const int* __restrict__ csr,
    const unsigned short* __restrict__ hW16, const float* __restrict__ disq,
    const float* __restrict__ bias, unsigned short* __restrict__ hout16, int n)
{
    const ushort4* hW4 = (const ushort4*)hW16;
    int wid  = (blockIdx.x * 256 + threadIdx.x) >> 6;
    if (wid >= n) return;
    int lane = threadIdx.x & 63;
    int fb = lane & 15;       // 8B chunk index within 128B row
    int es = lane >> 4;       // edge slot 0..3
    int j  = rowptr[wid];
    int r1 = rowptr[wid + 1];
    float4 v  = make_float4(0.f, 0.f, 0.f, 0.f);
    float4 v2 = make_float4(0.f, 0.f, 0.f, 0.f);
    if (es == 0) v = h4f(hW4[(size_t)wid * 16 + fb]);    // self-loop
    while (j < r1) {
        int cnt = min(r1 - j, 64);
        int idx = (lane < cnt) ? csr[j + lane] : 0;
        for (int jj = 0; jj < cnt; jj += 16) {
            int i0 = jj + es, i1 = jj + 4 + es, i2 = jj + 8 + es, i3 = jj + 12 + es;
            int s0 = __shfl(idx, i0 & 63);
            int s1 = __shfl(idx, i1 & 63);
            int s2 = __shfl(idx, i2 & 63);
            int s3 = __shfl(idx, i3 & 63);
            // 4 independent loads in flight; clamped/idle slots read row of idx=0 (L1 hit)
            float4 t0 = h4f(hW4[(size_t)s0 * 16 + fb]);
            float4 t1 = h4f(hW4[(size_t)s1 * 16 + fb]);
            float4 t2 = h4f(hW4[(size_t)s2 * 16 + fb]);
            float4 t3 = h4f(hW4[(size_t)s3 * 16 + fb]);
            if (i0 < cnt) { v.x  += t0.x; v.y  += t0.y; v.z  += t0.z; v.w  += t0.w; }
            if (i1 < cnt) { v2.x += t1.x; v2.y += t1.y; v2.z += t1.z; v2.w += t1.w; }
            if (i2 < cnt) { v.x  += t2.x; v.y  += t2.y; v.z  += t2.z; v.w  += t2.w; }
            if (i3 < cnt) { v2.x += t3.x; v2.y += t3.y; v2.z += t3.z; v2.w += t3.w; }
        }
        j += cnt;
    }
    v.x += v2.x; v.y += v2.y; v.z += v2.z; v.w += v2.w;
    v.x += __shfl_xor(v.x, 16); v.y += __shfl_xor(v.y, 16);
    v.z += __shfl_xor(v.z, 16); v.w += __shfl_xor(v.w, 16);
    v.x += __shfl_xor(v.x, 32); v.y += __shfl_xor(v.y, 32);
    v.z += __shfl_xor(v.z, 32); v.w += __shfl_xor(v.w, 32);
    if (es == 0) {
        float s = disq[wid];
        float4 b = ((const float4*)bias)[fb];
        float4 o;
        o.x = fmaxf(fmaf(s, v.x, b.x), 0.f);
        o.y = fmaxf(fmaf(s, v.y, b.y), 0.f);
        o.z = fmaxf(fmaf(s, v.z, b.z), 0.f);
        o.w = fmaxf(fmaf(s, v.w, b.w), 0.f);
        ((ushort4*)hout16)[(size_t)wid * 16 + fb] = f4h(o);
    }
}

// ============ final: t = relu(h@jkW5 + jkacc + jkb); pool by batch (LDS pre-reduce) ============
__global__ __launch_bounds__(256) void k_jkfin_pool(
    const unsigned short* __restrict__ A16,   // h [n][64] fp16
    const float* __restrict__ W,
    const float* __restrict__ jkacc,
    const float* __restrict__ bias,
    const int* __restrict__ batch,
    float* __restrict__ pooled,
    int n)
{
    __shared__ float Ws[64 * 64];
    __shared__ float As[64 * 68];
    const int tid  = threadIdx.x;
    const int col4 = (tid & 15) * 4;
    const int rowq = tid >> 4;
    const int base = blockIdx.x * 64;

    #pragma unroll
    for (int i = 0; i < 4; i++) {
        float4 v = *(const float4*)(W + (size_t)(i * 256 + tid) * 4);
        *(float4*)(Ws + (size_t)(i * 256 + tid) * 4) = v;
    }
    {
        const ushort4* Ah = (const ushort4*)A16;
        #pragma unroll
        for (int rr = 0; rr < 4; rr++) {
            int row = base + rowq + rr * 16;
            float4 v = make_float4(0.f, 0.f, 0.f, 0.f);
            if (row < n) v = h4f(Ah[(size_t)row * 16 + (tid & 15)]);
            *(float4*)(As + (size_t)(rowq + rr * 16) * 68 + col4) = v;
        }
    }
    __syncthreads();

    float4 acc[4];
    #pragma unroll
    for (int r = 0; r < 4; r++) acc[r] = make_float4(0.f, 0.f, 0.f, 0.f);
    #pragma unroll 8
    for (int k = 0; k < 64; k++) {
        float4 w = *(const float4*)(Ws + k * 64 + col4);
        float a0 = As[(rowq * 4 + 0) * 68 + k];
        float a1 = As[(rowq * 4 + 1) * 68 + k];
        float a2 = As[(rowq * 4 + 2) * 68 + k];
        float a3 = As[(rowq * 4 + 3) * 68 + k];
        acc[0].x = fmaf(a0, w.x, acc[0].x); acc[0].y = fmaf(a0, w.y, acc[0].y);
        acc[0].z = fmaf(a0, w.z, acc[0].z); acc[0].w = fmaf(a0, w.w, acc[0].w);
        acc[1].x = fmaf(a1, w.x, acc[1].x); acc[1].y = fmaf(a1, w.y, acc[1].y);
        acc[1].z = fmaf(a1, w.z, acc[1].z); acc[1].w = fmaf(a1, w.w, acc[1].w);
        acc[2].x = fmaf(a2, w.x, acc[2].x); acc[2].y = fmaf(a2, w.y, acc[2].y);
        acc[2].z = fmaf(a2, w.z, acc[2].z); acc[2].w = fmaf(a2, w.w, acc[2].w);
        acc[3].x = fmaf(a3, w.x, acc[3].x); acc[3].y = fmaf(a3, w.y, acc[3].y);
        acc[3].z = fmaf(a3, w.z, acc[3].z); acc[3].w = fmaf(a3, w.w, acc[3].w);
    }
    __syncthreads();               // Ws/As dead; reuse Ws as the pooling slab

    float* slab = Ws;              // [64 graphs][64 cols]
    #pragma unroll
    for (int i = tid; i < 4096; i += 256) slab[i] = 0.f;
    __syncthreads();

    float4 bb = *(const float4*)(bias + col4);
    int curg = -1;
    float4 s4 = make_float4(0.f, 0.f, 0.f, 0.f);
    #pragma unroll
    for (int r = 0; r < 4; r++) {
        int row = base + rowq * 4 + r;
        if (row < n) {
            float4 p = *(const float4*)(jkacc + (size_t)row * 64 + col4);
            float4 vv;
            vv.x = fmaxf(acc[r].x + p.x + bb.x, 0.f);
            vv.y = fmaxf(acc[r].y + p.y + bb.y, 0.f);
            vv.z = fmaxf(acc[r].z + p.z + bb.z, 0.f);
            vv.w = fmaxf(acc[r].w + p.w + bb.w, 0.f);
            int g = batch[row];
            if (g != curg) {
                if (curg >= 0) {
                    atomicAdd(&slab[curg * 64 + col4 + 0], s4.x);
                    atomicAdd(&slab[curg * 64 + col4 + 1], s4.y);
                    atomicAdd(&slab[curg * 64 + col4 + 2], s4.z);
                    atomicAdd(&slab[curg * 64 + col4 + 3], s4.w);
                }
                curg = g; s4 = vv;
            } else {
                s4.x += vv.x; s4.y += vv.y; s4.z += vv.z; s4.w += vv.w;
            }
        }
    }
    if (curg >= 0) {
        atomicAdd(&slab[curg * 64 + col4 + 0], s4.x);
        atomicAdd(&slab[curg * 64 + col4 + 1], s4.y);
        atomicAdd(&slab[curg * 64 + col4 + 2], s4.z);
        atomicAdd(&slab[curg * 64 + col4 + 3], s4.w);
    }
    __syncthreads();

    int g0 = batch[base];
    int g1 = batch[(base + 63 < n) ? (base + 63) : (n - 1)];
    int cnt = (g1 - g0 + 1) * 64;
    for (int i = tid; i < cnt; i += 256) {
        int g = g0 + (i >> 6);
        int c = i & 63;
        float v = slab[g * 64 + c];
        if (v != 0.f) atomicAdd(&pooled[g * 64 + c], v);
    }
}

// ============ head: one block per graph, LDS-staged, no register spill ============
__global__ __launch_bounds__(64) void k_head(
    const float* __restrict__ pooled,
    const float* __restrict__ W1, const float* __restrict__ b1,
    const float* __restrict__ W2, const float* __restrict__ b2,
    float* __restrict__ out)
{
    __shared__ float p[64];
    __shared__ float h1[64];
    __shared__ float lg[16];
    const int g = blockIdx.x;      // graph
    const int t = threadIdx.x;     // 64 threads

    p[t] = pooled[g * 64 + t];
    __syncthreads();

    float acc = b1[t];
    #pragma unroll 8
    for (int k = 0; k < 64; k++) acc = fmaf(p[k], W1[k * 64 + t], acc);
    h1[t] = fmaxf(acc, 0.f);
    __syncthreads();

    if (t < NCLS) {
        float a = b2[t];
        #pragma unroll 8
        for (int j = 0; j < 64; j++) a = fmaf(h1[j], W2[j * NCLS + t], a);
        lg[t] = a;
    }
    __syncthreads();

    if (t == 0) {
        float mx = lg[0];
        #pragma unroll
        for (int c = 1; c < NCLS; c++) mx = fmaxf(mx, lg[c]);
        float ssum = 0.f;
        float e[NCLS];
        #pragma unroll
        for (int c = 0; c < NCLS; c++) { e[c] = __expf(lg[c] - mx); ssum += e[c]; }
        float inv = 1.0f / ssum;
        #pragma unroll
        for (int c = 0; c < NCLS; c++) out[g * NCLS + c] = e[c] * inv;
    }
}

extern "C" void kernel_launch(void* const* d_in, const int* in_sizes, int n_in,
                              void* d_out, int out_size, void* d_ws, size_t ws_size,
                              hipStream_t stream) {
    (void)in_sizes; (void)n_in; (void)out_size; (void)ws_size;
    const float* x     = (const float*)d_in[0];
    const int*   ei    = (const int*)d_in[1];
    const int*   batch = (const int*)d_in[2];
    const float* W0    = (const float*)d_in[3];
    const float* b0    = (const float*)d_in[4];
    const float* Wh    = (const float*)d_in[5];
    const float* bh    = (const float*)d_in[6];
    const float* jkW   = (const float*)d_in[7];   // [384][64] = 6 stacked [64][64]
    const float* jkb   = (const float*)d_in[8];
    const float* W1    = (const float*)d_in[9];
    const float* b1    = (const float*)d_in[10];
    const float* W2    = (const float*)d_in[11];
    const float* b2    = (const float*)d_in[12];

    const int* src = ei;
    const int* dst = ei + NE;

    float*          fws    = (float*)d_ws;
    float*          disq   = fws;                                    // 100352 f
    unsigned short* hWb    = (unsigned short*)(disq + 100352);       // NN*64 fp16
    unsigned short* h16    = hWb + (size_t)NN * 64;                  // NN*64 fp16
    float*          jkacc  = (float*)(h16 + (size_t)NN * 64);        // NN*64 f
    float*          pooled = jkacc + (size_t)NN * 64;                // 4096 f
    int*            counts = (int*)(pooled + 4096);                  // 100352
    int*            rowptr = counts + 100352;                        // NN+1
    int*            wptr   = rowptr + 100352;                        // 100352
    int*            bsum   = wptr + 100352;                          // 512
    int*            csr    = bsum + 512;                             // NE

    const int NB_N = (NN + 255) / 256;                               // 391
    const int NB_E = (NE + 255) / 256;                               // 3907

    // ---- CSR build ----
    hipMemsetAsync(counts, 0, (size_t)NN * sizeof(int), stream);
    k_hist<<<NB_E, 256, 0, stream>>>(dst, counts, NE);
    k_blocksum<<<NB_N, 256, 0, stream>>>(counts, bsum, NN);
    k_scanbsum<<<1, 512, 0, stream>>>(bsum, NB_N);
    k_scanwrite<<<NB_N, 256, 0, stream>>>(counts, bsum, rowptr, wptr, disq, NN, NE);
    k_scatter_part<<<NB_E * 8, 256, 0, stream>>>(src, dst, wptr, csr, NE);

    // ---- layers: GEMM_l (folds h_{l-1}'s JK block for l>=1) + gather ----
    const int gemm_grid   = (NN + 63) / 64;                          // 1563
    const int gather_grid = (NN + 3) / 4;                            // 25000
    for (int l = 0; l < NLAY; l++) {
        const void*  A    = (l == 0) ? (const void*)x : (const void*)h16;
        int          a16  = (l == 0) ? 0 : 1;
        int          lda  = (l == 0) ? F_INF : HID;
        int          K    = (l == 0) ? F_INF : HID;
        const float* W    = (l == 0) ? W0 : (Wh + (size_t)(l - 1) * 64 * 64);
        const float* bias = (l == 0) ? b0 : (bh + (size_t)(l - 1) * 64);
        const float* jw   = (l == 0) ? nullptr : (jkW + (size_t)(l - 1) * 64 * 64);
        int          jkm  = (l == 0) ? 0 : ((l == 1) ? 1 : 2);

        k_gemm_dual<<<gemm_grid, 256, 0, stream>>>(A, lda, K, W, jw, disq,
                                                   hWb, jkacc, jkm, a16, NN);
        k_gather<<<gather_grid, 256, 0, stream>>>(rowptr, csr, hWb, disq, bias, h16, NN);
    }

    // ---- final: h5 @ jkW[5] + jkacc + jkb -> relu -> pool -> head ----
    hipMemsetAsync(pooled, 0, 64 * 64 * sizeof(float), stream);
    k_jkfin_pool<<<gemm_grid, 256, 0, stream>>>(h16, jkW + (size_t)5 * 64 * 64, jkacc,
                                                jkb, batch, pooled, NN);
    k_head<<<NGRAPH, 64, 0, stream>>>(pooled, W1, b1, W2, b2, (float*)d_out);
}

// Round 10
// 513.727 us; speedup vs baseline: 1.6287x; 1.0720x over previous
//
#include <hip/hip_runtime.h>
#include <hip/hip_fp16.h>

#define NN 100000
#define NE 1000000
#define F_INF 128
#define HID 64
#define NLAY 6
#define NCLS 10
#define NGRAPH 64
#define PART_SZ 12500   // NN/8 — contiguous node range per XCD partition
#define SCAT_BLKS (((NE + 2047) / 2048) * 8)   // 489*8 = 3912
#define GEMM_GRID ((NN + 63) / 64)             // 1563

__device__ __forceinline__ float4 h4f(ushort4 u) {
    __half2 lo = *reinterpret_cast<__half2*>(&u);
    __half2 hi = *reinterpret_cast<__half2*>(reinterpret_cast<unsigned short*>(&u) + 2);
    float2 a = __half22float2(lo);
    float2 b = __half22float2(hi);
    return make_float4(a.x, a.y, b.x, b.y);
}

__device__ __forceinline__ ushort4 f4h(float4 v) {
    __half2 lo = __floats2half2_rn(v.x, v.y);
    __half2 hi = __floats2half2_rn(v.z, v.w);
    ushort4 u;
    *reinterpret_cast<__half2*>(&u) = lo;
    *reinterpret_cast<__half2*>(reinterpret_cast<unsigned short*>(&u) + 2) = hi;
    return u;
}

// ================= CSR build =================
__global__ void k_hist(const int* __restrict__ dst, int* __restrict__ counts, int e) {
    int i0 = blockIdx.x * 1024 + threadIdx.x;
    #pragma unroll
    for (int k = 0; k < 4; k++) {
        int i = i0 + k * 256;
        if (i < e) atomicAdd(&counts[dst[i]], 1);
    }
}

__global__ void k_blocksum(const int* __restrict__ counts, int* __restrict__ bsum, int n) {
    int i = blockIdx.x * 256 + threadIdx.x;
    int v = (i < n) ? counts[i] : 0;
    #pragma unroll
    for (int off = 32; off >= 1; off >>= 1) v += __shfl_down(v, off);
    __shared__ int ws[4];
    if ((threadIdx.x & 63) == 0) ws[threadIdx.x >> 6] = v;
    __syncthreads();
    if (threadIdx.x == 0) bsum[blockIdx.x] = ws[0] + ws[1] + ws[2] + ws[3];
}

__global__ void k_scanbsum(int* __restrict__ bsum, int nb) {   // 1 block, 512 thr
    __shared__ int sh[512];
    int t = threadIdx.x;
    int v = (t < nb) ? bsum[t] : 0;
    sh[t] = v; __syncthreads();
    for (int off = 1; off < 512; off <<= 1) {
        int x = (t >= off) ? sh[t - off] : 0;
        __syncthreads();
        sh[t] += x; __syncthreads();
    }
    if (t < nb) bsum[t] = sh[t] - v;   // exclusive
}

__global__ void k_scanwrite(const int* __restrict__ counts, const int* __restrict__ bsumx,
                            int* __restrict__ rowptr, int* __restrict__ wptr,
                            float* __restrict__ disq, int n, int e) {
    __shared__ int sh[256];
    int t = threadIdx.x;
    int i = blockIdx.x * 256 + t;
    int v = (i < n) ? counts[i] : 0;
    sh[t] = v; __syncthreads();
    for (int off = 1; off < 256; off <<= 1) {
        int x = (t >= off) ? sh[t - off] : 0;
        __syncthreads();
        sh[t] += x; __syncthreads();
    }
    int excl = sh[t] - v + bsumx[blockIdx.x];
    if (i < n) {
        rowptr[i] = excl;
        wptr[i]   = excl;
        disq[i]   = rsqrtf((float)(v + 1));   // +1 self-loop
    }
    if (i == 0) rowptr[n] = e;
}

// ============ fused: XCD-partitioned scatter (8 edges/thread) + layer-0 GEMM ============
__global__ __launch_bounds__(256) void k_scatter_gemm0(
    const int* __restrict__ src, const int* __restrict__ dst,
    int* __restrict__ wptr, int* __restrict__ csr, int e,
    const float* __restrict__ x, const float* __restrict__ W0,
    const float* __restrict__ disq, unsigned short* __restrict__ C16, int n)
{
    __shared__ float Ws[64 * 64];
    __shared__ float As[64 * 68];

    if (blockIdx.x < SCAT_BLKS) {
        int part = blockIdx.x & 7;
        int i0 = (blockIdx.x >> 3) * 2048 + threadIdx.x;
        #pragma unroll
        for (int k = 0; k < 8; k++) {
            int i = i0 + k * 256;
            if (i < e) {
                int d = dst[i];
                if (d / PART_SZ == part) {
                    int pos = atomicAdd(&wptr[d], 1);
                    csr[pos] = src[i];
                }
            }
        }
        return;
    }

    const int tid  = threadIdx.x;
    const int col4 = (tid & 15) * 4;
    const int rowq = tid >> 4;
    const int base = (blockIdx.x - SCAT_BLKS) * 64;

    #pragma unroll
    for (int i = 0; i < 4; i++) {
        float4 v = *(const float4*)(W0 + (size_t)(i * 256 + tid) * 4);
        *(float4*)(Ws + (size_t)(i * 256 + tid) * 4) = v;
    }
    #pragma unroll
    for (int rr = 0; rr < 4; rr++) {
        int row = base + rowq + rr * 16;
        float4 v = make_float4(0.f, 0.f, 0.f, 0.f);
        if (row < n) v = *(const float4*)(x + (size_t)row * F_INF + col4);
        *(float4*)(As + (size_t)(rowq + rr * 16) * 68 + col4) = v;
    }
    __syncthreads();

    float4 acc[4];
    #pragma unroll
    for (int r = 0; r < 4; r++) acc[r] = make_float4(0.f, 0.f, 0.f, 0.f);

    for (int k0 = 0; k0 < F_INF; k0 += 64) {
        const bool more = (k0 + 64) < F_INF;
        float4 wreg[4], areg[4];
        if (more) {
            #pragma unroll
            for (int i = 0; i < 4; i++)
                wreg[i] = *(const float4*)(W0 + (size_t)(k0 + 64) * 64 + (i * 256 + tid) * 4);
            #pragma unroll
            for (int rr = 0; rr < 4; rr++) {
                int row = base + rowq + rr * 16;
                areg[rr] = make_float4(0.f, 0.f, 0.f, 0.f);
                if (row < n) areg[rr] = *(const float4*)(x + (size_t)row * F_INF + k0 + 64 + col4);
            }
        }
        #pragma unroll 8
        for (int k = 0; k < 64; k++) {
            float4 w = *(const float4*)(Ws + k * 64 + col4);
            float a0 = As[(rowq * 4 + 0) * 68 + k];
            float a1 = As[(rowq * 4 + 1) * 68 + k];
            float a2 = As[(rowq * 4 + 2) * 68 + k];
            float a3 = As[(rowq * 4 + 3) * 68 + k];
            acc[0].x = fmaf(a0, w.x, acc[0].x); acc[0].y = fmaf(a0, w.y, acc[0].y);
            acc[0].z = fmaf(a0, w.z, acc[0].z); acc[0].w = fmaf(a0, w.w, acc[0].w);
            acc[1].x = fmaf(a1, w.x, acc[1].x); acc[1].y = fmaf(a1, w.y, acc[1].y);
            acc[1].z = fmaf(a1, w.z, acc[1].z); acc[1].w = fmaf(a1, w.w, acc[1].w);
            acc[2].x = fmaf(a2, w.x, acc[2].x); acc[2].y = fmaf(a2, w.y, acc[2].y);
            acc[2].z = fmaf(a2, w.z, acc[2].z); acc[2].w = fmaf(a2, w.w, acc[2].w);
            acc[3].x = fmaf(a3, w.x, acc[3].x); acc[3].y = fmaf(a3, w.y, acc[3].y);
            acc[3].z = fmaf(a3, w.z, acc[3].z); acc[3].w = fmaf(a3, w.w, acc[3].w);
        }
        __syncthreads();
        if (more) {
            #pragma unroll
            for (int i = 0; i < 4; i++)
                *(float4*)(Ws + (size_t)(i * 256 + tid) * 4) = wreg[i];
            #pragma unroll
            for (int rr = 0; rr < 4; rr++)
                *(float4*)(As + (size_t)(rowq + rr * 16) * 68 + col4) = areg[rr];
            __syncthreads();
        }
    }

    #pragma unroll
    for (int r = 0; r < 4; r++) {
        int row = base + rowq * 4 + r;
        if (row < n) {
            float s = disq[row];
            float4 o;
            o.x = acc[r].x * s; o.y = acc[r].y * s;
            o.z = acc[r].z * s; o.w = acc[r].w * s;
            ((ushort4*)C16)[(size_t)row * 16 + (tid & 15)] = f4h(o);
        }
    }
}

// ============ dual GEMM layers 1-5 (K=64, fp16 A): C16 and jkacc ============
__global__ __launch_bounds__(256) void k_gemm_dual(
    const unsigned short* __restrict__ A16,
    const float* __restrict__ W,
    const float* __restrict__ jkw,
    const float* __restrict__ disq,
    unsigned short* __restrict__ C16,
    float* __restrict__ jkacc,
    int jk_mode, int n)
{
    __shared__ float Ws[64 * 64];
    __shared__ float Ws2[64 * 64];
    __shared__ float As[64 * 68];
    const int tid  = threadIdx.x;
    const int col4 = (tid & 15) * 4;
    const int rowq = tid >> 4;
    const int base = blockIdx.x * 64;

    #pragma unroll
    for (int i = 0; i < 4; i++) {
        float4 v = *(const float4*)(W + (size_t)(i * 256 + tid) * 4);
        *(float4*)(Ws + (size_t)(i * 256 + tid) * 4) = v;
        float4 v2 = *(const float4*)(jkw + (size_t)(i * 256 + tid) * 4);
        *(float4*)(Ws2 + (size_t)(i * 256 + tid) * 4) = v2;
    }
    {
        const ushort4* Ah = (const ushort4*)A16;
        #pragma unroll
        for (int rr = 0; rr < 4; rr++) {
            int row = base + rowq + rr * 16;
            float4 v = make_float4(0.f, 0.f, 0.f, 0.f);
            if (row < n) v = h4f(Ah[(size_t)row * 16 + (tid & 15)]);
            *(float4*)(As + (size_t)(rowq + rr * 16) * 68 + col4) = v;
        }
    }
    __syncthreads();

    float4 acc[4], acc2[4];
    #pragma unroll
    for (int r = 0; r < 4; r++) {
        acc[r]  = make_float4(0.f, 0.f, 0.f, 0.f);
        acc2[r] = make_float4(0.f, 0.f, 0.f, 0.f);
    }

    #pragma unroll 4
    for (int k = 0; k < 64; k++) {
        float4 w  = *(const float4*)(Ws  + k * 64 + col4);
        float4 w2 = *(const float4*)(Ws2 + k * 64 + col4);
        float a0 = As[(rowq * 4 + 0) * 68 + k];
        float a1 = As[(rowq * 4 + 1) * 68 + k];
        float a2 = As[(rowq * 4 + 2) * 68 + k];
        float a3 = As[(rowq * 4 + 3) * 68 + k];
        acc[0].x = fmaf(a0, w.x, acc[0].x); acc[0].y = fmaf(a0, w.y, acc[0].y);
        acc[0].z = fmaf(a0, w.z, acc[0].z); acc[0].w = fmaf(a0, w.w, acc[0].w);
        acc[1].x = fmaf(a1, w.x, acc[1].x); acc[1].y = fmaf(a1, w.y, acc[1].y);
        acc[1].z = fmaf(a1, w.z, acc[1].z); acc[1].w = fmaf(a1, w.w, acc[1].w);
        acc[2].x = fmaf(a2, w.x, acc[2].x); acc[2].y = fmaf(a2, w.y, acc[2].y);
        acc[2].z = fmaf(a2, w.z, acc[2].z); acc[2].w = fmaf(a2, w.w, acc[2].w);
        acc[3].x = fmaf(a3, w.x, acc[3].x); acc[3].y = fmaf(a3, w.y, acc[3].y);
        acc[3].z = fmaf(a3, w.z, acc[3].z); acc[3].w = fmaf(a3, w.w, acc[3].w);
        acc2[0].x = fmaf(a0, w2.x, acc2[0].x); acc2[0].y = fmaf(a0, w2.y, acc2[0].y);
        acc2[0].z = fmaf(a0, w2.z, acc2[0].z); acc2[0].w = fmaf(a0, w2.w, acc2[0].w);
        acc2[1].x = fmaf(a1, w2.x, acc2[1].x); acc2[1].y = fmaf(a1, w2.y, acc2[1].y);
        acc2[1].z = fmaf(a1, w2.z, acc2[1].z); acc2[1].w = fmaf(a1, w2.w, acc2[1].w);
        acc2[2].x = fmaf(a2, w2.x, acc2[2].x); acc2[2].y = fmaf(a2, w2.y, acc2[2].y);
        acc2[2].z = fmaf(a2, w2.z, acc2[2].z); acc2[2].w = fmaf(a2, w2.w, acc2[2].w);
        acc2[3].x = fmaf(a3, w2.x, acc2[3].x); acc2[3].y = fmaf(a3, w2.y, acc2[3].y);
        acc2[3].z = fmaf(a3, w2.z, acc2[3].z); acc2[3].w = fmaf(a3, w2.w, acc2[3].w);
    }

    #pragma unroll
    for (int r = 0; r < 4; r++) {
        int row = base + rowq * 4 + r;
        if (row < n) {
            float s = disq[row];
            float4 o;
            o.x = acc[r].x * s; o.y = acc[r].y * s;
            o.z = acc[r].z * s; o.w = acc[r].w * s;
            ((ushort4*)C16)[(size_t)row * 16 + (tid & 15)] = f4h(o);
            if (jk_mode == 1) {
                *(float4*)(jkacc + (size_t)row * 64 + col4) = acc2[r];
            } else {
                float4 p = *(const float4*)(jkacc + (size_t)row * 64 + col4);
                p.x += acc2[r].x; p.y += acc2[r].y;
                p.z += acc2[r].z; p.w += acc2[r].w;
                *(float4*)(jkacc + (size_t)row * 64 + col4) = p;
            }
        }
    }
}

// ============ gather: wave per node, fp16 in/out, 16 edges per step ============
__global__ __launch_bounds__(256) void k_gather(
    const int* __restrict__ rowptr, const int* __restrict__ csr,
    const unsigned short* __restrict__ hW16, const float* __restrict__ disq,
    const float* __restrict__ bias, unsigned short* __restrict__ hout16, int n)
{
    const ushort4* hW4 = (const ushort4*)hW16;
    int wid  = (blockIdx.x * 256 + threadIdx.x) >> 6;
    if (wid >= n) return;
    int lane = threadIdx.x & 63;
    int fb = lane & 15;
    int es = lane >> 4;
    int j  = rowptr[wid];
    int r1 = rowptr[wid + 1];
    float4 v  = make_float4(0.f, 0.f, 0.f, 0.f);
    float4 v2 = make_float4(0.f, 0.f, 0.f, 0.f);
    if (es == 0) v = h4f(hW4[(size_t)wid * 16 + fb]);    // self-loop
    while (j < r1) {
        int cnt = min(r1 - j, 64);
        int idx = (lane < cnt) ? csr[j + lane] : 0;
        for (int jj = 0; jj < cnt; jj += 16) {
            int i0 = jj + es, i1 = jj + 4 + es, i2 = jj + 8 + es, i3 = jj + 12 + es;
            int s0 = __shfl(idx, i0 & 63);
            int s1 = __shfl(idx, i1 & 63);
            int s2 = __shfl(idx, i2 & 63);
            int s3 = __shfl(idx, i3 & 63);
            float4 t0 = h4f(hW4[(size_t)s0 * 16 + fb]);
            float4 t1 = h4f(hW4[(size_t)s1 * 16 + fb]);
            float4 t2 = h4f(hW4[(size_t)s2 * 16 + fb]);
            float4 t3 = h4f(hW4[(size_t)s3 * 16 + fb]);
            if (i0 < cnt) { v.x  += t0.x; v.y  += t0.y; v.z  += t0.z; v.w  += t0.w; }
            if (i1 < cnt) { v2.x += t1.x; v2.y += t1.y; v2.z += t1.z; v2.w += t1.w; }
            if (i2 < cnt) { v.x  += t2.x; v.y  += t2.y; v.z  += t2.z; v.w  += t2.w; }
            if (i3 < cnt) { v2.x += t3.x; v2.y += t3.y; v2.z += t3.z; v2.w += t3.w; }
        }
        j += cnt;
    }
    v.x += v2.x; v.y += v2.y; v.z += v2.z; v.w += v2.w;
    v.x += __shfl_xor(v.x, 16); v.y += __shfl_xor(v.y, 16);
    v.z += __shfl_xor(v.z, 16); v.w += __shfl_xor(v.w, 16);
    v.x += __shfl_xor(v.x, 32); v.y += __shfl_xor(v.y, 32);
    v.z += __shfl_xor(v.z, 32); v.w += __shfl_xor(v.w, 32);
    if (es == 0) {
        float s = disq[wid];
        float4 b = ((const float4*)bias)[fb];
        float4 o;
        o.x = fmaxf(fmaf(s, v.x, b.x), 0.f);
        o.y = fmaxf(fmaf(s, v.y, b.y), 0.f);
        o.z = fmaxf(fmaf(s, v.z, b.z), 0.f);
        o.w = fmaxf(fmaf(s, v.w, b.w), 0.f);
        ((ushort4*)hout16)[(size_t)wid * 16 + fb] = f4h(o);
    }
}

// ============ final: t = relu(h@jkW5 + jkacc + jkb); pool by batch ============
__global__ __launch_bounds__(256) void k_jkfin_pool(
    const unsigned short* __restrict__ A16,
    const float* __restrict__ W,
    const float* __restrict__ jkacc,
    const float* __restrict__ bias,
    const int* __restrict__ batch,
    float* __restrict__ pooled,
    int n)
{
    __shared__ float Ws[64 * 64];
    __shared__ float As[64 * 68];
    const int tid  = threadIdx.x;
    const int col4 = (tid & 15) * 4;
    const int rowq = tid >> 4;
    const int base = blockIdx.x * 64;

    #pragma unroll
    for (int i = 0; i < 4; i++) {
        float4 v = *(const float4*)(W + (size_t)(i * 256 + tid) * 4);
        *(float4*)(Ws + (size_t)(i * 256 + tid) * 4) = v;
    }
    {
        const ushort4* Ah = (const ushort4*)A16;
        #pragma unroll
        for (int rr = 0; rr < 4; rr++) {
            int row = base + rowq + rr * 16;
            float4 v = make_float4(0.f, 0.f, 0.f, 0.f);
            if (row < n) v = h4f(Ah[(size_t)row * 16 + (tid & 15)]);
            *(float4*)(As + (size_t)(rowq + rr * 16) * 68 + col4) = v;
        }
    }
    __syncthreads();

    float4 acc[4];
    #pragma unroll
    for (int r = 0; r < 4; r++) acc[r] = make_float4(0.f, 0.f, 0.f, 0.f);
    #pragma unroll 8
    for (int k = 0; k < 64; k++) {
        float4 w = *(const float4*)(Ws + k * 64 + col4);
        float a0 = As[(rowq * 4 + 0) * 68 + k];
        float a1 = As[(rowq * 4 + 1) * 68 + k];
        float a2 = As[(rowq * 4 + 2) * 68 + k];
        float a3 = As[(rowq * 4 + 3) * 68 + k];
        acc[0].x = fmaf(a0, w.x, acc[0].x); acc[0].y = fmaf(a0, w.y, acc[0].y);
        acc[0].z = fmaf(a0, w.z, acc[0].z); acc[0].w = fmaf(a0, w.w, acc[0].w);
        acc[1].x = fmaf(a1, w.x, acc[1].x); acc[1].y = fmaf(a1, w.y, acc[1].y);
        acc[1].z = fmaf(a1, w.z, acc[1].z); acc[1].w = fmaf(a1, w.w, acc[1].w);
        acc[2].x = fmaf(a2, w.x, acc[2].x); acc[2].y = fmaf(a2, w.y, acc[2].y);
        acc[2].z = fmaf(a2, w.z, acc[2].z); acc[2].w = fmaf(a2, w.w, acc[2].w);
        acc[3].x = fmaf(a3, w.x, acc[3].x); acc[3].y = fmaf(a3, w.y, acc[3].y);
        acc[3].z = fmaf(a3, w.z, acc[3].z); acc[3].w = fmaf(a3, w.w, acc[3].w);
    }
    __syncthreads();

    float* slab = Ws;
    #pragma unroll
    for (int i = tid; i < 4096; i += 256) slab[i] = 0.f;
    __syncthreads();

    float4 bb = *(const float4*)(bias + col4);
    int curg = -1;
    float4 s4 = make_float4(0.f, 0.f, 0.f, 0.f);
    #pragma unroll
    for (int r = 0; r < 4; r++) {
        int row = base + rowq * 4 + r;
        if (row < n) {
            float4 p = *(const float4*)(jkacc + (size_t)row * 64 + col4);
            float4 vv;
            vv.x = fmaxf(acc[r].x + p.x + bb.x, 0.f);
            vv.y = fmaxf(acc[r].y + p.y + bb.y, 0.f);
            vv.z = fmaxf(acc[r].z + p.z + bb.z, 0.f);
            vv.w = fmaxf(acc[r].w + p.w + bb.w, 0.f);
            int g = batch[row];
            if (g != curg) {
                if (curg >= 0) {
                    atomicAdd(&slab[curg * 64 + col4 + 0], s4.x);
                    atomicAdd(&slab[curg * 64 + col4 + 1], s4.y);
                    atomicAdd(&slab[curg * 64 + col4 + 2], s4.z);
                    atomicAdd(&slab[curg * 64 + col4 + 3], s4.w);
                }
                curg = g; s4 = vv;
            } else {
                s4.x += vv.x; s4.y += vv.y; s4.z += vv.z; s4.w += vv.w;
            }
        }
    }
    if (curg >= 0) {
        atomicAdd(&slab[curg * 64 + col4 + 0], s4.x);
        atomicAdd(&slab[curg * 64 + col4 + 1], s4.y);
        atomicAdd(&slab[curg * 64 + col4 + 2], s4.z);
        atomicAdd(&slab[curg * 64 + col4 + 3], s4.w);
    }
    __syncthreads();

    int g0 = batch[base];
    int g1 = batch[(base + 63 < n) ? (base + 63) : (n - 1)];
    int cnt = (g1 - g0 + 1) * 64;
    for (int i = tid; i < cnt; i += 256) {
        int g = g0 + (i >> 6);
        int c = i & 63;
        float v = slab[g * 64 + c];
        if (v != 0.f) atomicAdd(&pooled[g * 64 + c], v);
    }
}

// ============ head ============
__global__ __launch_bounds__(64) void k_head(
    const float* __restrict__ pooled,
    const float* __restrict__ W1, const float* __restrict__ b1,
    const float* __restrict__ W2, const float* __restrict__ b2,
    float* __restrict__ out)
{
    __shared__ float p[64];
    __shared__ float h1[64];
    __shared__ float lg[16];
    const int g = blockIdx.x;
    const int t = threadIdx.x;

    p[t] = pooled[g * 64 + t];
    __syncthreads();

    float acc = b1[t];
    #pragma unroll 8
    for (int k = 0; k < 64; k++) acc = fmaf(p[k], W1[k * 64 + t], acc);
    h1[t] = fmaxf(acc, 0.f);
    __syncthreads();

    if (t < NCLS) {
        float a = b2[t];
        #pragma unroll 8
        for (int j = 0; j < 64; j++) a = fmaf(h1[j], W2[j * NCLS + t], a);
        lg[t] = a;
    }
    __syncthreads();

    if (t == 0) {
        float mx = lg[0];
        #pragma unroll
        for (int c = 1; c < NCLS; c++) mx = fmaxf(mx, lg[c]);
        float ssum = 0.f;
        float e[NCLS];
        #pragma unroll
        for (int c = 0; c < NCLS; c++) { e[c] = __expf(lg[c] - mx); ssum += e[c]; }
        float inv = 1.0f / ssum;
        #pragma unroll
        for (int c = 0; c < NCLS; c++) out[g * NCLS + c] = e[c] * inv;
    }
}

extern "C" void kernel_launch(void* const* d_in, const int* in_sizes, int n_in,
                              void* d_out, int out_size, void* d_ws, size_t ws_size,
                              hipStream_t stream) {
    (void)in_sizes; (void)n_in; (void)out_size; (void)ws_size;
    const float* x     = (const float*)d_in[0];
    const int*   ei    = (const int*)d_in[1];
    const int*   batch = (const int*)d_in[2];
    const float* W0    = (const float*)d_in[3];
    const float* b0    = (const float*)d_in[4];
    const float* Wh    = (const float*)d_in[5];
    const float* bh    = (const float*)d_in[6];
    const float* jkW   = (const float*)d_in[7];
    const float* jkb   = (const float*)d_in[8];
    const float* W1    = (const float*)d_in[9];
    const float* b1    = (const float*)d_in[10];
    const float* W2    = (const float*)d_in[11];
    const float* b2    = (const float*)d_in[12];

    const int* src = ei;
    const int* dst = ei + NE;

    float*          fws    = (float*)d_ws;
    float*          disq   = fws;
    unsigned short* hWb    = (unsigned short*)(disq + 100352);
    unsigned short* h16    = hWb + (size_t)NN * 64;
    float*          jkacc  = (float*)(h16 + (size_t)NN * 64);
    float*          pooled = jkacc + (size_t)NN * 64;
    int*            counts = (int*)(pooled + 4096);
    int*            rowptr = counts + 100352;
    int*            wptr   = rowptr + 100352;
    int*            bsum   = wptr + 100352;
    int*            csr    = bsum + 512;

    const int NB_N = (NN + 255) / 256;

    hipMemsetAsync(counts, 0, (size_t)NN * sizeof(int), stream);
    k_hist<<<(NE + 1023) / 1024, 256, 0, stream>>>(dst, counts, NE);
    k_blocksum<<<NB_N, 256, 0, stream>>>(counts, bsum, NN);
    k_scanbsum<<<1, 512, 0, stream>>>(bsum, NB_N);
    k_scanwrite<<<NB_N, 256, 0, stream>>>(counts, bsum, rowptr, wptr, disq, NN, NE);

    k_scatter_gemm0<<<SCAT_BLKS + GEMM_GRID, 256, 0, stream>>>(
        src, dst, wptr, csr, NE, x, W0, disq, hWb, NN);

    const int gather_grid = (NN + 3) / 4;
    k_gather<<<gather_grid, 256, 0, stream>>>(rowptr, csr, hWb, disq, b0, h16, NN);
    for (int l = 1; l < NLAY; l++) {
        const float* W   = Wh + (size_t)(l - 1) * 64 * 64;
        const float* jw  = jkW + (size_t)(l - 1) * 64 * 64;
        int          jkm = (l == 1) ? 1 : 2;
        k_gemm_dual<<<GEMM_GRID, 256, 0, stream>>>(h16, W, jw, disq, hWb, jkacc, jkm, NN);
        k_gather<<<gather_grid, 256, 0, stream>>>(rowptr, csr, hWb, disq,
                                                  bh + (size_t)(l - 1) * 64, h16, NN);
    }

    hipMemsetAsync(pooled, 0, 64 * 64 * sizeof(float), stream);
    k_jkfin_pool<<<GEMM_GRID, 256, 0, stream>>>(h16, jkW + (size_t)5 * 64 * 64, jkacc,
                                                jkb, batch, pooled, NN);
    k_head<<<NGRAPH, 64, 0, stream>>>(pooled, W1, b1, W2, b2, (float*)d_out);
}